// Round 1
// baseline (1078.371 us; speedup 1.0000x reference)
//
#include <hip/hip_runtime.h>

typedef unsigned short ushort_t;
typedef unsigned int uint_t;
typedef __attribute__((ext_vector_type(8))) short s8v;
typedef __attribute__((ext_vector_type(4))) short s4v;
typedef __attribute__((ext_vector_type(4))) float f4v;

#define MFMA(a,b,c) __builtin_amdgcn_mfma_f32_16x16x32_bf16(a,b,c,0,0,0)

#define GLDS16(g, l) \
  __builtin_amdgcn_global_load_lds((const __attribute__((address_space(1))) void*)(g), \
                                   (__attribute__((address_space(3))) void*)(l), 16, 0, 0)

__device__ __forceinline__ float bf2f(short s){
  return __uint_as_float(((uint_t)(ushort_t)s) << 16);
}
__device__ __forceinline__ ushort_t f2bf(float f){
  uint_t u = __float_as_uint(f);
  u += 0x7fffu + ((u >> 16) & 1u);
  return (ushort_t)(u >> 16);
}

// ---------------- conversions ----------------
// Transpose-convert: dst[R][C] (bf16) = src[C][R] (fp32). 64x64 tiles via LDS.
__global__ __launch_bounds__(256) void k_cvt_t(const float* __restrict__ src,
    ushort_t* __restrict__ dst, int R, int C){
  __shared__ ushort_t t[64*68];
  const int r0 = blockIdx.x*64, c0 = blockIdx.y*64;
  const int tid = threadIdx.x;
  const int cl = tid>>4, rl4 = (tid&15)*4;   // load: coalesced over r
  #pragma unroll
  for(int cc=0; cc<64; cc+=16){
    f4v v = *(const f4v*)(src + (size_t)(c0+cl+cc)*R + r0 + rl4);
    #pragma unroll
    for(int j=0;j<4;j++) t[(rl4+j)*68 + cl+cc] = f2bf(v[j]);
  }
  __syncthreads();
  const int rw = tid>>4, cw4 = (tid&15)*4;   // store: coalesced over c
  #pragma unroll
  for(int rr=0; rr<64; rr+=16){
    s4v o;
    #pragma unroll
    for(int j=0;j<4;j++) o[j] = (short)t[(rw+rr)*68 + cw4 + j];
    *(s4v*)(dst + (size_t)(r0+rw+rr)*C + c0 + cw4) = o;
  }
}
__global__ __launch_bounds__(256) void k_proj(const float* __restrict__ src,
    ushort_t* __restrict__ dst){
  int i = blockIdx.x*256 + threadIdx.x;
  if(i < 256*64) dst[i] = f2bf(src[i] * 0.3535533905932738f); // * DH^-1/4
}
__global__ __launch_bounds__(256) void k_f2b4(const float* __restrict__ s,
    ushort_t* __restrict__ d, int n4){
  int i = blockIdx.x*256 + threadIdx.x;
  if(i < n4){
    f4v v = ((const f4v*)s)[i];
    s4v o;
    #pragma unroll
    for(int j=0;j<4;j++) o[j] = (short)f2bf(v[j]);
    ((s4v*)d)[i] = o;
  }
}
__global__ __launch_bounds__(256) void k_zero(float* __restrict__ p, int n){
  int i = blockIdx.x*256 + threadIdx.x;
  if(i < n) p[i] = 0.f;
}

// ---------------- bf16 GEMM: C[M][N] = A[M][K] * Bt[N][K]^T ----------------
template<int MODE>
__global__ __launch_bounds__(256) void gemm_k(const ushort_t* __restrict__ A, int lda,
    const ushort_t* __restrict__ Bt, ushort_t* __restrict__ Cc, int ldc,
    const float* __restrict__ bias, int M, int N, int K)
{
  __shared__ ushort_t lA[128*32];
  __shared__ ushort_t lB[128*32];
  const int tid = threadIdx.x;
  const int wave = tid>>6, lane = tid&63, quad = lane>>4, lid = lane&15;
  // T1: XCD-aware bijective block swizzle (all launch grids have nwg%8==0).
  // Consecutive same-XCD blocks then share a B-panel in that XCD's L2.
  const int nwgx = gridDim.x;
  const int nwg  = nwgx * gridDim.y;
  const int orig = blockIdx.y * nwgx + blockIdx.x;
  const int swz  = (orig & 7) * (nwg >> 3) + (orig >> 3);
  const int row0 = (swz % nwgx)*128, col0 = (swz / nwgx)*128;
  const int wr = (wave>>1)*64, wc = (wave&1)*64;
  f4v acc[4][4];
  #pragma unroll
  for(int i=0;i<4;i++)
    #pragma unroll
    for(int j=0;j<4;j++){ f4v z = {0.f,0.f,0.f,0.f}; acc[i][j]=z; }

  const int srow = wave*16 + (lane>>2);
  const int scol = (lane&3)*8;
  const ushort_t* Ar0 = A  + (size_t)(row0+srow)*lda + scol;
  const ushort_t* Ar1 = Ar0 + (size_t)64*lda;
  const ushort_t* Br0 = Bt + (size_t)(col0+srow)*K + scol;
  const ushort_t* Br1 = Br0 + (size_t)64*K;
  ushort_t* lA0 = &lA[wave*512];
  ushort_t* lA1 = &lA[2048 + wave*512];
  ushort_t* lB0 = &lB[wave*512];
  ushort_t* lB1 = &lB[2048 + wave*512];

  for(int k0=0;k0<K;k0+=32){
    __syncthreads();
    GLDS16(Ar0 + k0, lA0);
    GLDS16(Ar1 + k0, lA1);
    GLDS16(Br0 + k0, lB0);
    GLDS16(Br1 + k0, lB1);
    __syncthreads();
    s8v af[4], bfv[4];
    #pragma unroll
    for(int i=0;i<4;i++) af[i]  = *(const s8v*)&lA[(wr+i*16+lid)*32 + quad*8];
    #pragma unroll
    for(int j=0;j<4;j++) bfv[j] = *(const s8v*)&lB[(wc+j*16+lid)*32 + quad*8];
    #pragma unroll
    for(int i=0;i<4;i++)
      #pragma unroll
      for(int j=0;j<4;j++)
        acc[i][j] = MFMA(af[i], bfv[j], acc[i][j]);
  }
  #pragma unroll
  for(int i=0;i<4;i++){
    const int row = row0 + wr + i*16 + quad*4;
    #pragma unroll
    for(int j=0;j<4;j++){
      const int col = col0 + wc + j*16 + lid;
      float bv = 0.f;
      if(MODE>=1) bv = bias[col];
      #pragma unroll
      for(int r=0;r<4;r++){
        float v = acc[i][j][r] + bv;
        if(MODE==2) v = v>0.f ? v : expm1f(v);
        Cc[(size_t)(row+r)*ldc + col] = f2bf(v);
      }
    }
  }
}

// ---------------- kv^T partials + ksum ----------------
// Grid (chunk=4, mt=4, bh=64). Each block: 16 slabs of 64 l-rows, 64 m-feats.
// K staged via global_load_lds with XOR col-block swizzle; V transposed via LDS;
// kp round-trips LDS (C-layout -> A-layout). Writes fp32 partial kv[m][dh]
// (no atomics); k_f2bt reduces 4 partials and transposes to bf16 [dh][m].
__global__ __launch_bounds__(256) void k_kv(const ushort_t* __restrict__ qkv,
    const ushort_t* __restrict__ projS,
    float* __restrict__ kvp, float* __restrict__ ksum)
{
  __shared__ ushort_t lK[64*64];       // [l][cb^(l&7) swizzled], no pad (glds)
  __shared__ ushort_t lvT[2][64*72];   // [dh][l], stride 72
  __shared__ ushort_t lkp[64*72];      // [m][l], stride 72
  const int chunk=blockIdx.x, mt=blockIdx.y, bh=blockIdx.z;
  const int h=bh&15, b=bh>>4;
  const int tid=threadIdx.x, wave=tid>>6, lane=tid&63, quad=lane>>4, lid=lane&15;

  // proj fragments held in registers for all iterations
  s8v pf[4][2];
  {
    const ushort_t* projM = projS + mt*64*64;
    #pragma unroll
    for(int n=0;n<4;n++)
      #pragma unroll
      for(int ks=0;ks<2;ks++)
        pf[n][ks] = *(const s8v*)(projM + (n*16+lid)*64 + ks*32 + quad*8);
  }
  f4v kvacc[4];
  #pragma unroll
  for(int j=0;j<4;j++){ f4v z={0.f,0.f,0.f,0.f}; kvacc[j]=z; }
  float ksacc[4] = {};

  // K staging pointers (swizzled source, lane-linear LDS dest)
  const int sl = tid>>3;               // slab row 0..31 (per round)
  const int gcb = (tid&7) ^ (sl&7);    // swizzled global col-block
  const size_t lbase = (size_t)(b*4096 + chunk*1024);
  const ushort_t* gK0 = qkv + (lbase + sl     )*3072 + 1024 + h*64 + gcb*8;
  const ushort_t* gK1 = qkv + (lbase + sl + 32)*3072 + 1024 + h*64 + gcb*8;
  ushort_t* lK0 = &lK[(wave*8     )*64];
  ushort_t* lK1 = &lK[(wave*8 + 32)*64];
  // V staging pointer: thread covers l=lane, dh wave*16..+16
  const ushort_t* gV = qkv + (lbase + lane)*3072 + 2048 + h*64 + wave*16;

  for(int it=0; it<16; it++){
    const int p = it&1;
    GLDS16(gK0, lK0);
    GLDS16(gK1, lK1);
    {
      s8v v0 = *(const s8v*)gV;
      s8v v1 = *(const s8v*)(gV + 8);
      #pragma unroll
      for(int jj=0;jj<8;jj++){
        lvT[p][(wave*16+jj  )*72 + lane] = (ushort_t)v0[jj];
        lvT[p][(wave*16+8+jj)*72 + lane] = (ushort_t)v1[jj];
      }
    }
    gK0 += 64*3072; gK1 += 64*3072; gV += 64*3072;
    __syncthreads();                 // B1: glds drained + vT visible
    // diag for this wave's 16 rows (4 lanes per row)
    float dv;
    {
      const int rl = wave*16 + (lane>>2);
      const int cb0 = 2*(lane&3);
      s8v u0 = *(const s8v*)&lK[rl*64 + ((cb0  )^(rl&7))*8];
      s8v u1 = *(const s8v*)&lK[rl*64 + ((cb0+1)^(rl&7))*8];
      float s = 0.f;
      #pragma unroll
      for(int jj=0;jj<8;jj++){
        float f0=bf2f(u0[jj]), f1=bf2f(u1[jj]);
        s += f0*f0 + f1*f1;
      }
      s += __shfl_xor(s,1,64); s += __shfl_xor(s,2,64);
      dv = s*(1.f/16.f);             // 0.5*dn^2 = 1/16
    }
    // dd MFMA from swizzled lK
    f4v dd[4];
    #pragma unroll
    for(int n=0;n<4;n++){ f4v z={0.f,0.f,0.f,0.f}; dd[n]=z; }
    {
      const int ra = wave*16 + lid;
      #pragma unroll
      for(int ks=0;ks<2;ks++){
        s8v af = *(const s8v*)&lK[ra*64 + ((ks*4+quad)^(ra&7))*8];
        #pragma unroll
        for(int n=0;n<4;n++) dd[n] = MFMA(af, pf[n][ks], dd[n]);
      }
    }
    // kp = exp(dd - diag) + eps -> lkp (A-layout)
    const int lrb = wave*16 + quad*4;
    #pragma unroll
    for(int n=0;n<4;n++){
      s4v pk;
      #pragma unroll
      for(int r=0;r<4;r++){
        float dg = __shfl(dv, (quad*4+r)*4, 64);
        float ekp = __expf(dd[n][r] - dg) + 1e-6f;
        ksacc[n] += ekp;
        pk[r] = (short)f2bf(ekp);
      }
      *(s4v*)&lkp[(n*16+lid)*72 + lrb] = pk;
    }
    __syncthreads();                 // B2: lkp ready
    #pragma unroll
    for(int ks=0;ks<2;ks++){
      s8v af = *(const s8v*)&lkp[(wave*16+lid)*72 + ks*32 + quad*8];
      #pragma unroll
      for(int j=0;j<4;j++){
        s8v bfr = *(const s8v*)&lvT[p][(j*16+lid)*72 + ks*32 + quad*8];
        kvacc[j] = MFMA(af, bfr, kvacc[j]);
      }
    }
  }
  // ksum: reduce across quads, one atomic per (n,lid) per wave
  #pragma unroll
  for(int n=0;n<4;n++){
    float s = ksacc[n];
    s += __shfl_xor(s,16,64); s += __shfl_xor(s,32,64);
    if(quad==0) atomicAdd(&ksum[((size_t)b*16+h)*256 + mt*64 + n*16 + lid], s);
  }
  // partial kv store: [m][dh], coalesced 64B per quad-group
  float* kvo = kvp + ((size_t)chunk*64 + bh)*16384;
  #pragma unroll
  for(int j=0;j<4;j++)
    #pragma unroll
    for(int r=0;r<4;r++)
      kvo[(mt*64 + wave*16 + quad*4 + r)*64 + j*16 + lid] = kvacc[j][r];
}

// ---------------- reduce 4 kv partials + transpose to bf16 [dh][m] ----------------
__global__ __launch_bounds__(256) void k_f2bt(const float* __restrict__ kvp,
    ushort_t* __restrict__ kvb)
{
  __shared__ ushort_t tb[64*68];   // [m-local][dh]
  const int mt=blockIdx.x, bh=blockIdx.y;
  const int tid=threadIdx.x;
  {
    const int ml=tid>>2, dg=(tid&3)*16;
    float s[16];
    #pragma unroll
    for(int e=0;e<16;e++) s[e]=0.f;
    #pragma unroll
    for(int c=0;c<4;c++){
      const float* pb = kvp + ((size_t)(c*64+bh)*256 + mt*64+ml)*64 + dg;
      #pragma unroll
      for(int e4=0;e4<4;e4++){
        f4v v = *(const f4v*)(pb + e4*4);
        #pragma unroll
        for(int j=0;j<4;j++) s[e4*4+j] += v[j];
      }
    }
    #pragma unroll
    for(int e=0;e<16;e++) tb[ml*68 + dg + e] = f2bf(s[e]);
  }
  __syncthreads();
  {
    const int dh=tid>>2, mg=(tid&3)*16;
    ushort_t* ob = kvb + (size_t)bh*16384 + (size_t)dh*256 + mt*64 + mg;
    #pragma unroll
    for(int e4=0;e4<4;e4++){
      s4v o;
      #pragma unroll
      for(int j=0;j<4;j++) o[j] = (short)tb[(mg+e4*4+j)*68 + dh];
      *(s4v*)(ob + e4*4) = o;
    }
  }
}

// ---------------- fused attention (per b,h,64 rows) ----------------
__global__ __launch_bounds__(256) void k_attn(const ushort_t* __restrict__ qkv,
    const ushort_t* __restrict__ projS, const ushort_t* __restrict__ kvT,
    const float* __restrict__ ksum, ushort_t* __restrict__ attnW)
{
  __shared__ ushort_t lqp[64*264];   // [l][m], stride 264
  __shared__ float ksl[256];
  const int lt=blockIdx.x, h=blockIdx.y, b=blockIdx.z;
  const int tid=threadIdx.x, wave=tid>>6, lane=tid&63, quad=lane>>4, lid=lane&15;
  const int l0 = lt*64;
  ksl[tid] = ksum[((size_t)b*16+h)*256 + tid];
  f4v dd[16];
  #pragma unroll
  for(int n=0;n<16;n++){ f4v z={0.f,0.f,0.f,0.f}; dd[n]=z; }
  const ushort_t* qbase = qkv + (size_t)(b*4096+l0+wave*16+lid)*3072 + h*64;
  #pragma unroll
  for(int ks=0;ks<2;ks++){
    s8v af = *(const s8v*)(qbase + ks*32 + quad*8);
    #pragma unroll
    for(int n=0;n<16;n++){
      s8v bfr = *(const s8v*)(projS + (n*16+lid)*64 + ks*32 + quad*8);
      dd[n] = MFMA(af, bfr, dd[n]);
    }
  }
  __syncthreads();                  // ksl ready
  float dnm[4];
  #pragma unroll
  for(int r=0;r<4;r++){
    const int lrow = wave*16 + quad*4 + r;
    float s = 0.f;
    #pragma unroll
    for(int n=0;n<16;n++){
      float e = __expf(dd[n][r]) + 1e-6f;
      s += e * ksl[n*16+lid];
      lqp[lrow*264 + n*16 + lid] = f2bf(e);
    }
    s += __shfl_xor(s,1,64); s += __shfl_xor(s,2,64);
    s += __shfl_xor(s,4,64); s += __shfl_xor(s,8,64);
    dnm[r] = s;
  }
  __syncthreads();                  // lqp ready
  f4v num[4];
  #pragma unroll
  for(int j=0;j<4;j++){ f4v z={0.f,0.f,0.f,0.f}; num[j]=z; }
  const ushort_t* kvb = kvT + ((size_t)b*16+h)*(64*256);
  #pragma unroll
  for(int ks=0;ks<8;ks++){
    s8v af = *(const s8v*)&lqp[(wave*16+lid)*264 + ks*32 + quad*8];
    #pragma unroll
    for(int j=0;j<4;j++){
      s8v bfr = *(const s8v*)(kvb + (size_t)(j*16+lid)*256 + ks*32 + quad*8);
      num[j] = MFMA(af, bfr, num[j]);
    }
  }
  #pragma unroll
  for(int j=0;j<4;j++)
    #pragma unroll
    for(int r=0;r<4;r++){
      const int row = b*4096 + l0 + wave*16 + quad*4 + r;
      attnW[(size_t)row*3072 + h*64 + j*16 + lid] = f2bf(num[j][r] / dnm[r]);
    }
}

// ---------------- LayerNorm ----------------
__device__ __forceinline__ float blockRed(float s, float* buf, int tid){
  #pragma unroll
  for(int o=1;o<64;o<<=1) s += __shfl_xor(s, o, 64);
  __syncthreads();
  if((tid&63)==0) buf[tid>>6] = s;
  __syncthreads();
  return buf[0]+buf[1]+buf[2]+buf[3];
}
template<int FINAL>
__global__ __launch_bounds__(256) void k_ln(const float* __restrict__ xres,
    const ushort_t* __restrict__ aa, int lda_a,
    const ushort_t* __restrict__ bbf, int lda_b,
    const float* __restrict__ g, const float* __restrict__ be,
    ushort_t* __restrict__ obf, int ldo, float* __restrict__ of)
{
  __shared__ float buf[4];
  const int row = blockIdx.x, tid = threadIdx.x;
  float v[4];
  if(FINAL==0){
    f4v xv = *(const f4v*)(xres + (size_t)row*1024 + tid*4);
    s4v av = *(const s4v*)(aa + (size_t)row*lda_a + tid*4);
    #pragma unroll
    for(int i=0;i<4;i++) v[i] = xv[i] + bf2f(av[i]);
  } else {
    s4v av = *(const s4v*)(aa + (size_t)row*lda_a + tid*4);
    s4v bv = *(const s4v*)(bbf + (size_t)row*lda_b + tid*4);
    #pragma unroll
    for(int i=0;i<4;i++) v[i] = bf2f(av[i]) + bf2f(bv[i]);
  }
  float s = v[0]+v[1]+v[2]+v[3];
  s = blockRed(s, buf, tid);
  const float mu = s * (1.f/1024.f);
  float q = 0.f;
  #pragma unroll
  for(int i=0;i<4;i++){ float d=v[i]-mu; q += d*d; }
  q = blockRed(q, buf, tid);
  const float rs = rsqrtf(q*(1.f/1024.f) + 1e-6f);
  const int col = tid*4;
  #pragma unroll
  for(int i=0;i<4;i++){
    float y = (v[i]-mu)*rs*g[col+i] + be[col+i];
    if(FINAL==0) obf[(size_t)row*ldo + col + i] = f2bf(y);
    else         of[(size_t)row*1024 + col + i] = y;
  }
}

// ---------------- launch ----------------
extern "C" void kernel_launch(void* const* d_in, const int* in_sizes, int n_in,
                              void* d_out, int out_size, void* d_ws, size_t ws_size,
                              hipStream_t stream) {
  (void)in_sizes; (void)n_in; (void)out_size; (void)ws_size;
  const float* x    = (const float*)d_in[0];
  const float* wq   = (const float*)d_in[1];
  const float* wk   = (const float*)d_in[2];
  const float* wv   = (const float*)d_in[3];
  const float* wo   = (const float*)d_in[4];
  const float* proj = (const float*)d_in[5];
  const float* ln1g = (const float*)d_in[6];
  const float* ln1b = (const float*)d_in[7];
  const float* ln2g = (const float*)d_in[8];
  const float* ln2b = (const float*)d_in[9];
  const float* w1   = (const float*)d_in[10];
  const float* b1   = (const float*)d_in[11];
  const float* w2   = (const float*)d_in[12];
  const float* b2   = (const float*)d_in[13];

  char* wsb = (char*)d_ws;
  size_t off = 0;
  auto alloc = [&](size_t bytes)->char*{
    char* p = wsb + off; off = (off + bytes + 255) & ~(size_t)255; return p;
  };
  ushort_t* wqkvT = (ushort_t*)alloc(3072ull*1024*2);
  ushort_t* woT   = (ushort_t*)alloc(1024ull*1024*2);
  ushort_t* w1T   = (ushort_t*)alloc(4096ull*1024*2);
  ushort_t* w2T   = (ushort_t*)alloc(1024ull*4096*2);
  ushort_t* projS = (ushort_t*)alloc(256*64*2);
  ushort_t* qkv   = (ushort_t*)alloc(16384ull*3072*2);   // 100.7 MB
  size_t zoff = off;
  float*    ksumb = (float*)alloc(4ull*16*256*4);
  size_t zlen = off - zoff;                               // zeroed each call
  ushort_t* kvb   = (ushort_t*)alloc(4ull*16*64*256*2);
  // total ws use: ~134 MB

  // overlays on qkv column bands (each band [16384][1024], row stride 3072):
  ushort_t* out1 = qkv;           // q band — dead after k_attn
  ushort_t* ao   = qkv + 1024;    // k band — dead after k_kv
  ushort_t* attn = qkv + 2048;    // v band — dead after k_kv
  ushort_t* ffn  = qkv + 2048;    // v band again — attn dead after wo-GEMM
  // d_out timeline: xb (bf16 x, QKV phase) -> kvp (fp32 kv partials, 64 MB)
  //                 -> hbuf (FFN phase) -> final fp32 out
  ushort_t* xb   = (ushort_t*)d_out;
  float*    kvp  = (float*)d_out;
  ushort_t* hb   = (ushort_t*)d_out;

  // weight conversions (transposed to [N][K])
  k_cvt_t<<<dim3(16,16),256,0,stream>>>(wq, wqkvT,                1024, 1024);
  k_cvt_t<<<dim3(16,16),256,0,stream>>>(wk, wqkvT + 1024ull*1024, 1024, 1024);
  k_cvt_t<<<dim3(16,16),256,0,stream>>>(wv, wqkvT + 2048ull*1024, 1024, 1024);
  k_cvt_t<<<dim3(16,16),256,0,stream>>>(wo, woT, 1024, 1024);
  k_cvt_t<<<dim3(64,16),256,0,stream>>>(w1, w1T, 4096, 1024);
  k_cvt_t<<<dim3(16,64),256,0,stream>>>(w2, w2T, 1024, 4096);
  k_proj<<<64,256,0,stream>>>(proj, projS);
  k_f2b4<<<16384,256,0,stream>>>(x, xb, 16384*1024/4);
  {
    int nz = (int)(zlen/4);
    k_zero<<<(nz+255)/256,256,0,stream>>>((float*)(wsb+zoff), nz);
  }

  // QKV projection: [16384,3072] = xb[16384,1024] * wqkvT^T
  gemm_k<0><<<dim3(128,24),256,0,stream>>>(xb, 1024, wqkvT, qkv, 3072, nullptr, 16384, 3072, 1024);
  // kv partials + ksum (xb dead; kvp overlays d_out)
  k_kv<<<dim3(4,4,64),256,0,stream>>>(qkv, projS, kvp, ksumb);
  // reduce partials + transpose -> bf16 kvb [dh][m]
  k_f2bt<<<dim3(4,64),256,0,stream>>>(kvp, kvb);
  // attention numerator/denominator -> v band
  k_attn<<<dim3(64,16,4),256,0,stream>>>(qkv, projS, kvb, ksumb, attn);
  // output projection (v band -> k band) + LN1 (-> q band)
  gemm_k<0><<<dim3(128,8),256,0,stream>>>(attn, 3072, woT, ao, 3072, nullptr, 16384, 1024, 1024);
  k_ln<0><<<16384,256,0,stream>>>(x, ao, 3072, nullptr, 0, ln1g, ln1b, out1, 3072, nullptr);
  // FFN in 2 row-chunks of 8192 (hbuf in d_out; kvp dead by now)
  for(int c=0;c<2;c++){
    const size_t ro = (size_t)c*8192*3072;
    gemm_k<2><<<dim3(64,32),256,0,stream>>>(out1 + ro, 3072, w1T, hb, 4096, b1, 8192, 4096, 1024);
    gemm_k<1><<<dim3(64,8),256,0,stream>>>(hb, 4096, w2T, ffn + ro, 3072, b2, 8192, 1024, 4096);
  }
  // LN2 -> fp32 out (overwrites all of d_out)
  k_ln<1><<<16384,256,0,stream>>>(nullptr, out1, 3072, ffn, 3072, ln2g, ln2b, nullptr, 0, (float*)d_out);
}

// Round 2
// 959.869 us; speedup vs baseline: 1.1235x; 1.1235x over previous
//
#include <hip/hip_runtime.h>

typedef unsigned short ushort_t;
typedef unsigned int uint_t;
typedef __attribute__((ext_vector_type(8))) short s8v;
typedef __attribute__((ext_vector_type(4))) short s4v;
typedef __attribute__((ext_vector_type(4))) float f4v;

#define MFMA(a,b,c) __builtin_amdgcn_mfma_f32_16x16x32_bf16(a,b,c,0,0,0)

#define GLDS16(g, l) \
  __builtin_amdgcn_global_load_lds((const __attribute__((address_space(1))) void*)(g), \
                                   (__attribute__((address_space(3))) void*)(l), 16, 0, 0)

__device__ __forceinline__ float bf2f(short s){
  return __uint_as_float(((uint_t)(ushort_t)s) << 16);
}
__device__ __forceinline__ ushort_t f2bf(float f){
  uint_t u = __float_as_uint(f);
  u += 0x7fffu + ((u >> 16) & 1u);
  return (ushort_t)(u >> 16);
}

// ---------------- conversions ----------------
__global__ __launch_bounds__(256) void k_cvt_t(const float* __restrict__ src,
    ushort_t* __restrict__ dst, int R, int C){
  __shared__ ushort_t t[64*68];
  const int r0 = blockIdx.x*64, c0 = blockIdx.y*64;
  const int tid = threadIdx.x;
  const int cl = tid>>4, rl4 = (tid&15)*4;
  #pragma unroll
  for(int cc=0; cc<64; cc+=16){
    f4v v = *(const f4v*)(src + (size_t)(c0+cl+cc)*R + r0 + rl4);
    #pragma unroll
    for(int j=0;j<4;j++) t[(rl4+j)*68 + cl+cc] = f2bf(v[j]);
  }
  __syncthreads();
  const int rw = tid>>4, cw4 = (tid&15)*4;
  #pragma unroll
  for(int rr=0; rr<64; rr+=16){
    s4v o;
    #pragma unroll
    for(int j=0;j<4;j++) o[j] = (short)t[(rw+rr)*68 + cw4 + j];
    *(s4v*)(dst + (size_t)(r0+rw+rr)*C + c0 + cw4) = o;
  }
}
__global__ __launch_bounds__(256) void k_proj(const float* __restrict__ src,
    ushort_t* __restrict__ dst){
  int i = blockIdx.x*256 + threadIdx.x;
  if(i < 256*64) dst[i] = f2bf(src[i] * 0.3535533905932738f);
}
__global__ __launch_bounds__(256) void k_f2b4(const float* __restrict__ s,
    ushort_t* __restrict__ d, int n4){
  int i = blockIdx.x*256 + threadIdx.x;
  if(i < n4){
    f4v v = ((const f4v*)s)[i];
    s4v o;
    #pragma unroll
    for(int j=0;j<4;j++) o[j] = (short)f2bf(v[j]);
    ((s4v*)d)[i] = o;
  }
}
__global__ __launch_bounds__(256) void k_zero(float* __restrict__ p, int n){
  int i = blockIdx.x*256 + threadIdx.x;
  if(i < n) p[i] = 0.f;
}

// ============ 256x256 8-phase bf16 GEMM: C[M][N] = A[M][K] * Bt[N][K]^T ============
// 512 threads / 8 waves (2M x 4N). BK=64, double-buffered LDS (128 KiB).
// T2: XOR-swizzled LDS via pre-swizzled glds source (both-sides rule).
// T3/T4: per-phase half-tile staging with counted vmcnt(2) at phases 4/8.
// T5: setprio(1) around each 16-MFMA cluster.
template<int MODE>
__global__ __launch_bounds__(512,2) void gemm8(const ushort_t* __restrict__ A, int lda,
    const ushort_t* __restrict__ Bt, int ldb, ushort_t* __restrict__ Cc, int ldc,
    const float* __restrict__ bias, int M, int N, int K)
{
  __shared__ ushort_t lsh[4][256*64];   // [buf*2+isB][row*64 + k]
  const int tid = threadIdx.x;
  const int wave = tid>>6, lane = tid&63, quad = lane>>4, lid = lane&15;
  const int wm = wave>>2, wn = wave&3;
  // T1 bijective XCD swizzle (all grids have nwg%8==0)
  const int nwgx = gridDim.x;
  const int nwg  = nwgx * gridDim.y;
  const int orig = blockIdx.y*nwgx + blockIdx.x;
  const int swz  = (orig&7)*(nwg>>3) + (orig>>3);
  const int row0 = (swz % nwgx)*256, col0 = (swz / nwgx)*256;

  // staging: per glds, one wave fills 8 rows x 64 k (1024 B). source k pre-swizzled.
  const int srow = lane>>3;                 // row within the wave's 8-row group
  const int scol = ((lane&7) ^ srow)*8;     // swizzled k-elem offset
  const ushort_t* gA = A  + (size_t)(row0 + wave*8 + srow)*lda + scol;
  const ushort_t* gB = Bt + (size_t)(col0 + wave*8 + srow)*ldb + scol;
  const int ldsw = wave*512;                // wave-uniform LDS dest (elems)

  // ds_read fragment offsets (apply same XOR involution on read)
  const int aoff = (wm*128 + lid)*64;
  const int boff = (wn*64  + lid)*64;
  const int k0s  = (quad*8)        ^ ((lid&7)<<3);
  const int k1s  = (32 + quad*8)   ^ ((lid&7)<<3);

  f4v acc[8][4];
  #pragma unroll
  for(int m=0;m<8;m++)
    #pragma unroll
    for(int n=0;n<4;n++){ f4v z={0.f,0.f,0.f,0.f}; acc[m][n]=z; }
  s8v af[4][2], bf[4][2];

  const int KT = K>>6;
  const int NP = KT>>1;

#define STG(buf, isB, half, kt) do{ \
    const ushort_t* _g = ((isB)? gB : gA) + (size_t)((half)*128)*((isB)? ldb : lda) + (size_t)(kt)*64; \
    GLDS16(_g, &lsh[(buf)*2+(isB)][(half)*8192 + ldsw]); \
    GLDS16(_g + (size_t)64*((isB)? ldb : lda), &lsh[(buf)*2+(isB)][(half)*8192 + 4096 + ldsw]); \
  }while(0)

#define DSA(buf, mh) do{ \
    const ushort_t* _l = &lsh[(buf)*2][aoff + (mh)*4096]; \
    _Pragma("unroll") \
    for(int _m=0;_m<4;_m++){ \
      af[_m][0] = *(const s8v*)(_l + _m*1024 + k0s); \
      af[_m][1] = *(const s8v*)(_l + _m*1024 + k1s); \
    } \
  }while(0)

#define DSB(buf, nh) do{ \
    const ushort_t* _l = &lsh[(buf)*2+1][boff]; \
    _Pragma("unroll") \
    for(int _n=0;_n<2;_n++){ \
      bf[(nh)*2+_n][0] = *(const s8v*)(_l + ((nh)*2+_n)*1024 + k0s); \
      bf[(nh)*2+_n][1] = *(const s8v*)(_l + ((nh)*2+_n)*1024 + k1s); \
    } \
  }while(0)

#define MMP(mh, nh) do{ \
    __builtin_amdgcn_s_setprio(1); \
    _Pragma("unroll") \
    for(int _m=0;_m<4;_m++) \
      _Pragma("unroll") \
      for(int _n=0;_n<2;_n++){ \
        acc[(mh)*4+_m][(nh)*2+_n] = MFMA(af[_m][0], bf[(nh)*2+_n][0], acc[(mh)*4+_m][(nh)*2+_n]); \
        acc[(mh)*4+_m][(nh)*2+_n] = MFMA(af[_m][1], bf[(nh)*2+_n][1], acc[(mh)*4+_m][(nh)*2+_n]); \
      } \
    __builtin_amdgcn_s_setprio(0); \
  }while(0)

#define BARX  __builtin_amdgcn_s_barrier()
#define LGKM0 do{ asm volatile("s_waitcnt lgkmcnt(0)" ::: "memory"); __builtin_amdgcn_sched_barrier(0); }while(0)
#define VM2   do{ asm volatile("s_waitcnt vmcnt(2)"   ::: "memory"); __builtin_amdgcn_sched_barrier(0); }while(0)

  // prologue: stage tile0 fully + tile1.A0; wait tile0 landed (2 in flight)
  STG(0,0,0,0); STG(0,0,1,0); STG(0,1,0,0); STG(0,1,1,0);
  STG(1,0,0,1);
  VM2;
  BARX;

  for(int p=0; p<NP; p++){
    const int t1 = 2*p+1;
    const int t2 = (2*p+2 < KT)? 2*p+2 : KT-1;
    const int t3 = (2*p+3 < KT)? 2*p+3 : KT-1;
    // P1: buf0 (mh0,nh0); stage t1.A1 -> buf1.A1
    DSA(0,0); DSB(0,0); STG(1,0,1,t1);
    asm volatile("s_waitcnt lgkmcnt(8)" ::: "memory");
    BARX; LGKM0; MMP(0,0); BARX;
    // P2: buf0 (mh0,nh1); stage t1.B0,B1 -> buf1.B
    DSB(0,1); STG(1,1,0,t1); STG(1,1,1,t1);
    BARX; LGKM0; MMP(0,1); BARX;
    // P3: buf0 (mh1,nh0); stage t2.A0 -> buf0.A0 (free since P2 end)
    DSA(0,1); STG(0,0,0,t2);
    BARX; LGKM0; MMP(1,0); BARX;
    // P4: buf0 (mh1,nh1); vmcnt ensures t1 (buf1) fully landed
    MMP(1,1); VM2; BARX;
    // P5: buf1 (mh0,nh0); stage t2.A1 -> buf0.A1 (free since P4 end)
    DSA(1,0); DSB(1,0); STG(0,0,1,t2);
    asm volatile("s_waitcnt lgkmcnt(8)" ::: "memory");
    BARX; LGKM0; MMP(0,0); BARX;
    // P6: buf1 (mh0,nh1); stage t2.B0,B1 -> buf0.B (free since P4 end)
    DSB(1,1); STG(0,1,0,t2); STG(0,1,1,t2);
    BARX; LGKM0; MMP(0,1); BARX;
    // P7: buf1 (mh1,nh0); stage t3.A0 -> buf1.A0 (free since P6 end)
    DSA(1,1); STG(1,0,0,t3);
    BARX; LGKM0; MMP(1,0); BARX;
    // P8: buf1 (mh1,nh1); vmcnt ensures t2 (buf0) fully landed
    MMP(1,1); VM2; BARX;
  }
  asm volatile("s_waitcnt vmcnt(0)" ::: "memory");

  #pragma unroll
  for(int m=0;m<8;m++){
    const int row = row0 + wm*128 + (m>>2)*64 + (m&3)*16 + quad*4;
    #pragma unroll
    for(int n=0;n<4;n++){
      const int col = col0 + wn*64 + n*16 + lid;
      float bv = 0.f;
      if(MODE>=1) bv = bias[col];
      #pragma unroll
      for(int r=0;r<4;r++){
        float v = acc[m][n][r] + bv;
        if(MODE==2) v = v>0.f ? v : expm1f(v);
        Cc[(size_t)(row+r)*ldc + col] = f2bf(v);
      }
    }
  }
#undef STG
#undef DSA
#undef DSB
#undef MMP
#undef BARX
#undef LGKM0
#undef VM2
}

// ---------------- kv^T partials + ksum ----------------
__global__ __launch_bounds__(256) void k_kv(const ushort_t* __restrict__ qkv,
    const ushort_t* __restrict__ projS,
    float* __restrict__ kvp, float* __restrict__ ksum)
{
  __shared__ ushort_t lK[64*64];
  __shared__ ushort_t lvT[2][64*72];
  __shared__ ushort_t lkp[64*72];
  const int chunk=blockIdx.x, mt=blockIdx.y, bh=blockIdx.z;
  const int h=bh&15, b=bh>>4;
  const int tid=threadIdx.x, wave=tid>>6, lane=tid&63, quad=lane>>4, lid=lane&15;

  s8v pf[4][2];
  {
    const ushort_t* projM = projS + mt*64*64;
    #pragma unroll
    for(int n=0;n<4;n++)
      #pragma unroll
      for(int ks=0;ks<2;ks++)
        pf[n][ks] = *(const s8v*)(projM + (n*16+lid)*64 + ks*32 + quad*8);
  }
  f4v kvacc[4];
  #pragma unroll
  for(int j=0;j<4;j++){ f4v z={0.f,0.f,0.f,0.f}; kvacc[j]=z; }
  float ksacc[4] = {};

  const int sl = tid>>3;
  const int gcb = (tid&7) ^ (sl&7);
  const size_t lbase = (size_t)(b*4096 + chunk*1024);
  const ushort_t* gK0 = qkv + (lbase + sl     )*3072 + 1024 + h*64 + gcb*8;
  const ushort_t* gK1 = qkv + (lbase + sl + 32)*3072 + 1024 + h*64 + gcb*8;
  ushort_t* lK0 = &lK[(wave*8     )*64];
  ushort_t* lK1 = &lK[(wave*8 + 32)*64];
  const ushort_t* gV = qkv + (lbase + lane)*3072 + 2048 + h*64 + wave*16;

  for(int it=0; it<16; it++){
    const int p = it&1;
    GLDS16(gK0, lK0);
    GLDS16(gK1, lK1);
    {
      s8v v0 = *(const s8v*)gV;
      s8v v1 = *(const s8v*)(gV + 8);
      #pragma unroll
      for(int jj=0;jj<8;jj++){
        lvT[p][(wave*16+jj  )*72 + lane] = (ushort_t)v0[jj];
        lvT[p][(wave*16+8+jj)*72 + lane] = (ushort_t)v1[jj];
      }
    }
    gK0 += 64*3072; gK1 += 64*3072; gV += 64*3072;
    __syncthreads();
    float dv;
    {
      const int rl = wave*16 + (lane>>2);
      const int cb0 = 2*(lane&3);
      s8v u0 = *(const s8v*)&lK[rl*64 + ((cb0  )^(rl&7))*8];
      s8v u1 = *(const s8v*)&lK[rl*64 + ((cb0+1)^(rl&7))*8];
      float s = 0.f;
      #pragma unroll
      for(int jj=0;jj<8;jj++){
        float f0=bf2f(u0[jj]), f1=bf2f(u1[jj]);
        s += f0*f0 + f1*f1;
      }
      s += __shfl_xor(s,1,64); s += __shfl_xor(s,2,64);
      dv = s*(1.f/16.f);
    }
    f4v dd[4];
    #pragma unroll
    for(int n=0;n<4;n++){ f4v z={0.f,0.f,0.f,0.f}; dd[n]=z; }
    {
      const int ra = wave*16 + lid;
      #pragma unroll
      for(int ks=0;ks<2;ks++){
        s8v af = *(const s8v*)&lK[ra*64 + ((ks*4+quad)^(ra&7))*8];
        #pragma unroll
        for(int n=0;n<4;n++) dd[n] = MFMA(af, pf[n][ks], dd[n]);
      }
    }
    const int lrb = wave*16 + quad*4;
    #pragma unroll
    for(int n=0;n<4;n++){
      s4v pk;
      #pragma unroll
      for(int r=0;r<4;r++){
        float dg = __shfl(dv, (quad*4+r)*4, 64);
        float ekp = __expf(dd[n][r] - dg) + 1e-6f;
        ksacc[n] += ekp;
        pk[r] = (short)f2bf(ekp);
      }
      *(s4v*)&lkp[(n*16+lid)*72 + lrb] = pk;
    }
    __syncthreads();
    #pragma unroll
    for(int ks=0;ks<2;ks++){
      s8v af = *(const s8v*)&lkp[(wave*16+lid)*72 + ks*32 + quad*8];
      #pragma unroll
      for(int j=0;j<4;j++){
        s8v bfr = *(const s8v*)&lvT[p][(j*16+lid)*72 + ks*32 + quad*8];
        kvacc[j] = MFMA(af, bfr, kvacc[j]);
      }
    }
  }
  #pragma unroll
  for(int n=0;n<4;n++){
    float s = ksacc[n];
    s += __shfl_xor(s,16,64); s += __shfl_xor(s,32,64);
    if(quad==0) atomicAdd(&ksum[((size_t)b*16+h)*256 + mt*64 + n*16 + lid], s);
  }
  float* kvo = kvp + ((size_t)chunk*64 + bh)*16384;
  #pragma unroll
  for(int j=0;j<4;j++)
    #pragma unroll
    for(int r=0;r<4;r++)
      kvo[(mt*64 + wave*16 + quad*4 + r)*64 + j*16 + lid] = kvacc[j][r];
}

// ---------------- reduce 4 kv partials + transpose to bf16 [dh][m] ----------------
__global__ __launch_bounds__(256) void k_f2bt(const float* __restrict__ kvp,
    ushort_t* __restrict__ kvb)
{
  __shared__ ushort_t tb[64*68];
  const int mt=blockIdx.x, bh=blockIdx.y;
  const int tid=threadIdx.x;
  {
    const int ml=tid>>2, dg=(tid&3)*16;
    float s[16];
    #pragma unroll
    for(int e=0;e<16;e++) s[e]=0.f;
    #pragma unroll
    for(int c=0;c<4;c++){
      const float* pb = kvp + ((size_t)(c*64+bh)*256 + mt*64+ml)*64 + dg;
      #pragma unroll
      for(int e4=0;e4<4;e4++){
        f4v v = *(const f4v*)(pb + e4*4);
        #pragma unroll
        for(int j=0;j<4;j++) s[e4*4+j] += v[j];
      }
    }
    #pragma unroll
    for(int e=0;e<16;e++) tb[ml*68 + dg + e] = f2bf(s[e]);
  }
  __syncthreads();
  {
    const int dh=tid>>2, mg=(tid&3)*16;
    ushort_t* ob = kvb + (size_t)bh*16384 + (size_t)dh*256 + mt*64 + mg;
    #pragma unroll
    for(int e4=0;e4<4;e4++){
      s4v o;
      #pragma unroll
      for(int j=0;j<4;j++) o[j] = (short)tb[(mg+e4*4+j)*68 + dh];
      *(s4v*)(ob + e4*4) = o;
    }
  }
}

// ---------------- fused attention (per b,h,64 rows) ----------------
__global__ __launch_bounds__(256) void k_attn(const ushort_t* __restrict__ qkv,
    const ushort_t* __restrict__ projS, const ushort_t* __restrict__ kvT,
    const float* __restrict__ ksum, ushort_t* __restrict__ attnW)
{
  __shared__ ushort_t lqp[64*264];
  __shared__ float ksl[256];
  const int lt=blockIdx.x, h=blockIdx.y, b=blockIdx.z;
  const int tid=threadIdx.x, wave=tid>>6, lane=tid&63, quad=lane>>4, lid=lane&15;
  const int l0 = lt*64;
  ksl[tid] = ksum[((size_t)b*16+h)*256 + tid];
  f4v dd[16];
  #pragma unroll
  for(int n=0;n<16;n++){ f4v z={0.f,0.f,0.f,0.f}; dd[n]=z; }
  const ushort_t* qbase = qkv + (size_t)(b*4096+l0+wave*16+lid)*3072 + h*64;
  #pragma unroll
  for(int ks=0;ks<2;ks++){
    s8v af = *(const s8v*)(qbase + ks*32 + quad*8);
    #pragma unroll
    for(int n=0;n<16;n++){
      s8v bfr = *(const s8v*)(projS + (n*16+lid)*64 + ks*32 + quad*8);
      dd[n] = MFMA(af, bfr, dd[n]);
    }
  }
  __syncthreads();
  float dnm[4];
  #pragma unroll
  for(int r=0;r<4;r++){
    const int lrow = wave*16 + quad*4 + r;
    float s = 0.f;
    #pragma unroll
    for(int n=0;n<16;n++){
      float e = __expf(dd[n][r]) + 1e-6f;
      s += e * ksl[n*16+lid];
      lqp[lrow*264 + n*16 + lid] = f2bf(e);
    }
    s += __shfl_xor(s,1,64); s += __shfl_xor(s,2,64);
    s += __shfl_xor(s,4,64); s += __shfl_xor(s,8,64);
    dnm[r] = s;
  }
  __syncthreads();
  f4v num[4];
  #pragma unroll
  for(int j=0;j<4;j++){ f4v z={0.f,0.f,0.f,0.f}; num[j]=z; }
  const ushort_t* kvb = kvT + ((size_t)b*16+h)*(64*256);
  #pragma unroll
  for(int ks=0;ks<8;ks++){
    s8v af = *(const s8v*)&lqp[(wave*16+lid)*264 + ks*32 + quad*8];
    #pragma unroll
    for(int j=0;j<4;j++){
      s8v bfr = *(const s8v*)(kvb + (size_t)(j*16+lid)*256 + ks*32 + quad*8);
      num[j] = MFMA(af, bfr, num[j]);
    }
  }
  #pragma unroll
  for(int j=0;j<4;j++)
    #pragma unroll
    for(int r=0;r<4;r++){
      const int row = b*4096 + l0 + wave*16 + quad*4 + r;
      attnW[(size_t)row*3072 + h*64 + j*16 + lid] = f2bf(num[j][r] / dnm[r]);
    }
}

// ---------------- LayerNorm ----------------
__device__ __forceinline__ float blockRed(float s, float* buf, int tid){
  #pragma unroll
  for(int o=1;o<64;o<<=1) s += __shfl_xor(s, o, 64);
  __syncthreads();
  if((tid&63)==0) buf[tid>>6] = s;
  __syncthreads();
  return buf[0]+buf[1]+buf[2]+buf[3];
}
template<int FINAL>
__global__ __launch_bounds__(256) void k_ln(const float* __restrict__ xres,
    const ushort_t* __restrict__ aa, int lda_a,
    const ushort_t* __restrict__ bbf, int lda_b,
    const float* __restrict__ g, const float* __restrict__ be,
    ushort_t* __restrict__ obf, int ldo, float* __restrict__ of)
{
  __shared__ float buf[4];
  const int row = blockIdx.x, tid = threadIdx.x;
  float v[4];
  if(FINAL==0){
    f4v xv = *(const f4v*)(xres + (size_t)row*1024 + tid*4);
    s4v av = *(const s4v*)(aa + (size_t)row*lda_a + tid*4);
    #pragma unroll
    for(int i=0;i<4;i++) v[i] = xv[i] + bf2f(av[i]);
  } else {
    s4v av = *(const s4v*)(aa + (size_t)row*lda_a + tid*4);
    s4v bv = *(const s4v*)(bbf + (size_t)row*lda_b + tid*4);
    #pragma unroll
    for(int i=0;i<4;i++) v[i] = bf2f(av[i]) + bf2f(bv[i]);
  }
  float s = v[0]+v[1]+v[2]+v[3];
  s = blockRed(s, buf, tid);
  const float mu = s * (1.f/1024.f);
  float q = 0.f;
  #pragma unroll
  for(int i=0;i<4;i++){ float d=v[i]-mu; q += d*d; }
  q = blockRed(q, buf, tid);
  const float rs = rsqrtf(q*(1.f/1024.f) + 1e-6f);
  const int col = tid*4;
  #pragma unroll
  for(int i=0;i<4;i++){
    float y = (v[i]-mu)*rs*g[col+i] + be[col+i];
    if(FINAL==0) obf[(size_t)row*ldo + col + i] = f2bf(y);
    else         of[(size_t)row*1024 + col + i] = y;
  }
}

// ---------------- launch ----------------
extern "C" void kernel_launch(void* const* d_in, const int* in_sizes, int n_in,
                              void* d_out, int out_size, void* d_ws, size_t ws_size,
                              hipStream_t stream) {
  (void)in_sizes; (void)n_in; (void)out_size; (void)ws_size;
  const float* x    = (const float*)d_in[0];
  const float* wq   = (const float*)d_in[1];
  const float* wk   = (const float*)d_in[2];
  const float* wv   = (const float*)d_in[3];
  const float* wo   = (const float*)d_in[4];
  const float* proj = (const float*)d_in[5];
  const float* ln1g = (const float*)d_in[6];
  const float* ln1b = (const float*)d_in[7];
  const float* ln2g = (const float*)d_in[8];
  const float* ln2b = (const float*)d_in[9];
  const float* w1   = (const float*)d_in[10];
  const float* b1   = (const float*)d_in[11];
  const float* w2   = (const float*)d_in[12];
  const float* b2   = (const float*)d_in[13];

  char* wsb = (char*)d_ws;
  size_t off = 0;
  auto alloc = [&](size_t bytes)->char*{
    char* p = wsb + off; off = (off + bytes + 255) & ~(size_t)255; return p;
  };
  ushort_t* wqkvT = (ushort_t*)alloc(3072ull*1024*2);
  ushort_t* woT   = (ushort_t*)alloc(1024ull*1024*2);
  ushort_t* w1T   = (ushort_t*)alloc(4096ull*1024*2);
  ushort_t* w2T   = (ushort_t*)alloc(1024ull*4096*2);
  ushort_t* projS = (ushort_t*)alloc(256*64*2);
  ushort_t* qkv   = (ushort_t*)alloc(16384ull*3072*2);
  size_t zoff = off;
  float*    ksumb = (float*)alloc(4ull*16*256*4);
  size_t zlen = off - zoff;
  ushort_t* kvb   = (ushort_t*)alloc(4ull*16*64*256*2);

  ushort_t* out1 = qkv;
  ushort_t* ao   = qkv + 1024;
  ushort_t* attn = qkv + 2048;
  ushort_t* ffn  = qkv + 2048;
  ushort_t* xb   = (ushort_t*)d_out;
  float*    kvp  = (float*)d_out;
  ushort_t* hb   = (ushort_t*)d_out;

  k_cvt_t<<<dim3(16,16),256,0,stream>>>(wq, wqkvT,                1024, 1024);
  k_cvt_t<<<dim3(16,16),256,0,stream>>>(wk, wqkvT + 1024ull*1024, 1024, 1024);
  k_cvt_t<<<dim3(16,16),256,0,stream>>>(wv, wqkvT + 2048ull*1024, 1024, 1024);
  k_cvt_t<<<dim3(16,16),256,0,stream>>>(wo, woT, 1024, 1024);
  k_cvt_t<<<dim3(64,16),256,0,stream>>>(w1, w1T, 4096, 1024);
  k_cvt_t<<<dim3(16,64),256,0,stream>>>(w2, w2T, 1024, 4096);
  k_proj<<<64,256,0,stream>>>(proj, projS);
  k_f2b4<<<16384,256,0,stream>>>(x, xb, 16384*1024/4);
  {
    int nz = (int)(zlen/4);
    k_zero<<<(nz+255)/256,256,0,stream>>>((float*)(wsb+zoff), nz);
  }

  // QKV projection
  gemm8<0><<<dim3(64,12),512,0,stream>>>(xb, 1024, wqkvT, 1024, qkv, 3072, nullptr, 16384, 3072, 1024);
  k_kv<<<dim3(4,4,64),256,0,stream>>>(qkv, projS, kvp, ksumb);
  k_f2bt<<<dim3(4,64),256,0,stream>>>(kvp, kvb);
  k_attn<<<dim3(64,16,4),256,0,stream>>>(qkv, projS, kvb, ksumb, attn);
  // output projection + LN1
  gemm8<0><<<dim3(64,4),512,0,stream>>>(attn, 3072, woT, 1024, ao, 3072, nullptr, 16384, 1024, 1024);
  k_ln<0><<<16384,256,0,stream>>>(x, ao, 3072, nullptr, 0, ln1g, ln1b, out1, 3072, nullptr);
  // FFN in 2 row-chunks of 8192
  for(int c=0;c<2;c++){
    const size_t ro = (size_t)c*8192*3072;
    gemm8<2><<<dim3(32,16),512,0,stream>>>(out1 + ro, 3072, w1T, 1024, hb, 4096, b1, 8192, 4096, 1024);
    gemm8<1><<<dim3(32,4),512,0,stream>>>(hb, 4096, w2T, 4096, ffn + ro, 3072, b2, 8192, 1024, 4096);
  }
  k_ln<1><<<16384,256,0,stream>>>(nullptr, out1, 3072, ffn, 3072, ln2g, ln2b, nullptr, 0, (float*)d_out);
}

// Round 3
// 922.588 us; speedup vs baseline: 1.1689x; 1.0404x over previous
//
#include <hip/hip_runtime.h>

typedef unsigned short ushort_t;
typedef unsigned int uint_t;
typedef __attribute__((ext_vector_type(8))) short s8v;
typedef __attribute__((ext_vector_type(4))) short s4v;
typedef __attribute__((ext_vector_type(4))) float f4v;

#define MFMA(a,b,c) __builtin_amdgcn_mfma_f32_16x16x32_bf16(a,b,c,0,0,0)

#define GLDS16(g, l) \
  __builtin_amdgcn_global_load_lds((const __attribute__((address_space(1))) void*)(g), \
                                   (__attribute__((address_space(3))) void*)(l), 16, 0, 0)

__device__ __forceinline__ float bf2f(short s){
  return __uint_as_float(((uint_t)(ushort_t)s) << 16);
}
__device__ __forceinline__ ushort_t f2bf(float f){
  uint_t u = __float_as_uint(f);
  u += 0x7fffu + ((u >> 16) & 1u);
  return (ushort_t)(u >> 16);
}

// ---------------- conversions ----------------
__global__ __launch_bounds__(256) void k_cvt_t(const float* __restrict__ src,
    ushort_t* __restrict__ dst, int R, int C){
  __shared__ ushort_t t[64*68];
  const int r0 = blockIdx.x*64, c0 = blockIdx.y*64;
  const int tid = threadIdx.x;
  const int cl = tid>>4, rl4 = (tid&15)*4;
  #pragma unroll
  for(int cc=0; cc<64; cc+=16){
    f4v v = *(const f4v*)(src + (size_t)(c0+cl+cc)*R + r0 + rl4);
    #pragma unroll
    for(int j=0;j<4;j++) t[(rl4+j)*68 + cl+cc] = f2bf(v[j]);
  }
  __syncthreads();
  const int rw = tid>>4, cw4 = (tid&15)*4;
  #pragma unroll
  for(int rr=0; rr<64; rr+=16){
    s4v o;
    #pragma unroll
    for(int j=0;j<4;j++) o[j] = (short)t[(rw+rr)*68 + cw4 + j];
    *(s4v*)(dst + (size_t)(r0+rw+rr)*C + c0 + cw4) = o;
  }
}
__global__ __launch_bounds__(256) void k_proj(const float* __restrict__ src,
    ushort_t* __restrict__ dst){
  int i = blockIdx.x*256 + threadIdx.x;
  if(i < 256*64) dst[i] = f2bf(src[i] * 0.3535533905932738f);
}
__global__ __launch_bounds__(256) void k_f2b4(const float* __restrict__ s,
    ushort_t* __restrict__ d, int n4){
  int i = blockIdx.x*256 + threadIdx.x;
  if(i < n4){
    f4v v = ((const f4v*)s)[i];
    s4v o;
    #pragma unroll
    for(int j=0;j<4;j++) o[j] = (short)f2bf(v[j]);
    ((s4v*)d)[i] = o;
  }
}
__global__ __launch_bounds__(256) void k_zero(float* __restrict__ p, int n){
  int i = blockIdx.x*256 + threadIdx.x;
  if(i < n) p[i] = 0.f;
}

// ============ 256x256 8-phase bf16 GEMM: C[M][N] = A[M][K] * Bt[N][K]^T ============
template<int MODE>
__global__ __launch_bounds__(512,2) void gemm8(const ushort_t* __restrict__ A, int lda,
    const ushort_t* __restrict__ Bt, int ldb, ushort_t* __restrict__ Cc, int ldc,
    const float* __restrict__ bias, int M, int N, int K)
{
  __shared__ ushort_t lsh[4][256*64];   // [buf*2+isB][row*64 + k]
  const int tid = threadIdx.x;
  const int wave = tid>>6, lane = tid&63, quad = lane>>4, lid = lane&15;
  const int wm = wave>>2, wn = wave&3;
  const int nwgx = gridDim.x;
  const int nwg  = nwgx * gridDim.y;
  const int orig = blockIdx.y*nwgx + blockIdx.x;
  const int swz  = (orig&7)*(nwg>>3) + (orig>>3);
  const int row0 = (swz % nwgx)*256, col0 = (swz / nwgx)*256;

  const int srow = lane>>3;
  const int scol = ((lane&7) ^ srow)*8;
  const ushort_t* gA = A  + (size_t)(row0 + wave*8 + srow)*lda + scol;
  const ushort_t* gB = Bt + (size_t)(col0 + wave*8 + srow)*ldb + scol;
  const int ldsw = wave*512;

  const int aoff = (wm*128 + lid)*64;
  const int boff = (wn*64  + lid)*64;
  const int k0s  = (quad*8)        ^ ((lid&7)<<3);
  const int k1s  = (32 + quad*8)   ^ ((lid&7)<<3);

  f4v acc[8][4];
  #pragma unroll
  for(int m=0;m<8;m++)
    #pragma unroll
    for(int n=0;n<4;n++){ f4v z={0.f,0.f,0.f,0.f}; acc[m][n]=z; }
  s8v af[4][2], bf[4][2];

  const int KT = K>>6;
  const int NP = KT>>1;

#define STG(buf, isB, half, kt) do{ \
    const ushort_t* _g = ((isB)? gB : gA) + (size_t)((half)*128)*((isB)? ldb : lda) + (size_t)(kt)*64; \
    GLDS16(_g, &lsh[(buf)*2+(isB)][(half)*8192 + ldsw]); \
    GLDS16(_g + (size_t)64*((isB)? ldb : lda), &lsh[(buf)*2+(isB)][(half)*8192 + 4096 + ldsw]); \
  }while(0)

#define DSA(buf, mh) do{ \
    const ushort_t* _l = &lsh[(buf)*2][aoff + (mh)*4096]; \
    _Pragma("unroll") \
    for(int _m=0;_m<4;_m++){ \
      af[_m][0] = *(const s8v*)(_l + _m*1024 + k0s); \
      af[_m][1] = *(const s8v*)(_l + _m*1024 + k1s); \
    } \
  }while(0)

#define DSB(buf, nh) do{ \
    const ushort_t* _l = &lsh[(buf)*2+1][boff]; \
    _Pragma("unroll") \
    for(int _n=0;_n<2;_n++){ \
      bf[(nh)*2+_n][0] = *(const s8v*)(_l + ((nh)*2+_n)*1024 + k0s); \
      bf[(nh)*2+_n][1] = *(const s8v*)(_l + ((nh)*2+_n)*1024 + k1s); \
    } \
  }while(0)

#define MMP(mh, nh) do{ \
    __builtin_amdgcn_s_setprio(1); \
    _Pragma("unroll") \
    for(int _m=0;_m<4;_m++) \
      _Pragma("unroll") \
      for(int _n=0;_n<2;_n++){ \
        acc[(mh)*4+_m][(nh)*2+_n] = MFMA(af[_m][0], bf[(nh)*2+_n][0], acc[(mh)*4+_m][(nh)*2+_n]); \
        acc[(mh)*4+_m][(nh)*2+_n] = MFMA(af[_m][1], bf[(nh)*2+_n][1], acc[(mh)*4+_m][(nh)*2+_n]); \
      } \
    __builtin_amdgcn_s_setprio(0); \
  }while(0)

#define BARX  __builtin_amdgcn_s_barrier()
#define LGKM0 do{ asm volatile("s_waitcnt lgkmcnt(0)" ::: "memory"); __builtin_amdgcn_sched_barrier(0); }while(0)
#define VM2   do{ asm volatile("s_waitcnt vmcnt(2)"   ::: "memory"); __builtin_amdgcn_sched_barrier(0); }while(0)

  STG(0,0,0,0); STG(0,0,1,0); STG(0,1,0,0); STG(0,1,1,0);
  STG(1,0,0,1);
  VM2;
  BARX;

  for(int p=0; p<NP; p++){
    const int t1 = 2*p+1;
    const int t2 = (2*p+2 < KT)? 2*p+2 : KT-1;
    const int t3 = (2*p+3 < KT)? 2*p+3 : KT-1;
    DSA(0,0); DSB(0,0); STG(1,0,1,t1);
    asm volatile("s_waitcnt lgkmcnt(8)" ::: "memory");
    BARX; LGKM0; MMP(0,0); BARX;
    DSB(0,1); STG(1,1,0,t1); STG(1,1,1,t1);
    BARX; LGKM0; MMP(0,1); BARX;
    DSA(0,1); STG(0,0,0,t2);
    BARX; LGKM0; MMP(1,0); BARX;
    MMP(1,1); VM2; BARX;
    DSA(1,0); DSB(1,0); STG(0,0,1,t2);
    asm volatile("s_waitcnt lgkmcnt(8)" ::: "memory");
    BARX; LGKM0; MMP(0,0); BARX;
    DSB(1,1); STG(0,1,0,t2); STG(0,1,1,t2);
    BARX; LGKM0; MMP(0,1); BARX;
    DSA(1,1); STG(1,0,0,t3);
    BARX; LGKM0; MMP(1,0); BARX;
    MMP(1,1); VM2; BARX;
  }
  asm volatile("s_waitcnt vmcnt(0)" ::: "memory");

  #pragma unroll
  for(int m=0;m<8;m++){
    const int row = row0 + wm*128 + (m>>2)*64 + (m&3)*16 + quad*4;
    #pragma unroll
    for(int n=0;n<4;n++){
      const int col = col0 + wn*64 + n*16 + lid;
      float bv = 0.f;
      if(MODE>=1) bv = bias[col];
      #pragma unroll
      for(int r=0;r<4;r++){
        float v = acc[m][n][r] + bv;
        if(MODE==2) v = v>0.f ? v : expm1f(v);
        Cc[(size_t)(row+r)*ldc + col] = f2bf(v);
      }
    }
  }
#undef STG
#undef DSA
#undef DSB
#undef MMP
#undef BARX
#undef LGKM0
#undef VM2
}

// ---------------- kv^T partials + ksum ----------------
__global__ __launch_bounds__(256) void k_kv(const ushort_t* __restrict__ qkv,
    const ushort_t* __restrict__ projS,
    float* __restrict__ kvp, float* __restrict__ ksum)
{
  __shared__ ushort_t lK[64*64];
  __shared__ ushort_t lvT[2][64*72];
  __shared__ ushort_t lkp[64*72];
  const int chunk=blockIdx.x, mt=blockIdx.y, bh=blockIdx.z;
  const int h=bh&15, b=bh>>4;
  const int tid=threadIdx.x, wave=tid>>6, lane=tid&63, quad=lane>>4, lid=lane&15;

  s8v pf[4][2];
  {
    const ushort_t* projM = projS + mt*64*64;
    #pragma unroll
    for(int n=0;n<4;n++)
      #pragma unroll
      for(int ks=0;ks<2;ks++)
        pf[n][ks] = *(const s8v*)(projM + (n*16+lid)*64 + ks*32 + quad*8);
  }
  f4v kvacc[4];
  #pragma unroll
  for(int j=0;j<4;j++){ f4v z={0.f,0.f,0.f,0.f}; kvacc[j]=z; }
  float ksacc[4] = {};

  const int sl = tid>>3;
  const int gcb = (tid&7) ^ (sl&7);
  const size_t lbase = (size_t)(b*4096 + chunk*1024);
  const ushort_t* gK0 = qkv + (lbase + sl     )*3072 + 1024 + h*64 + gcb*8;
  const ushort_t* gK1 = qkv + (lbase + sl + 32)*3072 + 1024 + h*64 + gcb*8;
  ushort_t* lK0 = &lK[(wave*8     )*64];
  ushort_t* lK1 = &lK[(wave*8 + 32)*64];
  const ushort_t* gV = qkv + (lbase + lane)*3072 + 2048 + h*64 + wave*16;

  for(int it=0; it<16; it++){
    const int p = it&1;
    GLDS16(gK0, lK0);
    GLDS16(gK1, lK1);
    {
      s8v v0 = *(const s8v*)gV;
      s8v v1 = *(const s8v*)(gV + 8);
      #pragma unroll
      for(int jj=0;jj<8;jj++){
        lvT[p][(wave*16+jj  )*72 + lane] = (ushort_t)v0[jj];
        lvT[p][(wave*16+8+jj)*72 + lane] = (ushort_t)v1[jj];
      }
    }
    gK0 += 64*3072; gK1 += 64*3072; gV += 64*3072;
    __syncthreads();
    float dv;
    {
      const int rl = wave*16 + (lane>>2);
      const int cb0 = 2*(lane&3);
      s8v u0 = *(const s8v*)&lK[rl*64 + ((cb0  )^(rl&7))*8];
      s8v u1 = *(const s8v*)&lK[rl*64 + ((cb0+1)^(rl&7))*8];
      float s = 0.f;
      #pragma unroll
      for(int jj=0;jj<8;jj++){
        float f0=bf2f(u0[jj]), f1=bf2f(u1[jj]);
        s += f0*f0 + f1*f1;
      }
      s += __shfl_xor(s,1,64); s += __shfl_xor(s,2,64);
      dv = s*(1.f/16.f);
    }
    f4v dd[4];
    #pragma unroll
    for(int n=0;n<4;n++){ f4v z={0.f,0.f,0.f,0.f}; dd[n]=z; }
    {
      const int ra = wave*16 + lid;
      #pragma unroll
      for(int ks=0;ks<2;ks++){
        s8v af = *(const s8v*)&lK[ra*64 + ((ks*4+quad)^(ra&7))*8];
        #pragma unroll
        for(int n=0;n<4;n++) dd[n] = MFMA(af, pf[n][ks], dd[n]);
      }
    }
    const int lrb = wave*16 + quad*4;
    #pragma unroll
    for(int n=0;n<4;n++){
      s4v pk;
      #pragma unroll
      for(int r=0;r<4;r++){
        float dg = __shfl(dv, (quad*4+r)*4, 64);
        float ekp = __expf(dd[n][r] - dg) + 1e-6f;
        ksacc[n] += ekp;
        pk[r] = (short)f2bf(ekp);
      }
      *(s4v*)&lkp[(n*16+lid)*72 + lrb] = pk;
    }
    __syncthreads();
    #pragma unroll
    for(int ks=0;ks<2;ks++){
      s8v af = *(const s8v*)&lkp[(wave*16+lid)*72 + ks*32 + quad*8];
      #pragma unroll
      for(int j=0;j<4;j++){
        s8v bfr = *(const s8v*)&lvT[p][(j*16+lid)*72 + ks*32 + quad*8];
        kvacc[j] = MFMA(af, bfr, kvacc[j]);
      }
    }
  }
  #pragma unroll
  for(int n=0;n<4;n++){
    float s = ksacc[n];
    s += __shfl_xor(s,16,64); s += __shfl_xor(s,32,64);
    if(quad==0) atomicAdd(&ksum[((size_t)b*16+h)*256 + mt*64 + n*16 + lid], s);
  }
  float* kvo = kvp + ((size_t)chunk*64 + bh)*16384;
  #pragma unroll
  for(int j=0;j<4;j++)
    #pragma unroll
    for(int r=0;r<4;r++)
      kvo[(mt*64 + wave*16 + quad*4 + r)*64 + j*16 + lid] = kvacc[j][r];
}

// ---------------- reduce 4 kv partials + transpose to bf16 [dh][m] ----------------
__global__ __launch_bounds__(256) void k_f2bt(const float* __restrict__ kvp,
    ushort_t* __restrict__ kvb)
{
  __shared__ ushort_t tb[64*68];
  const int mt=blockIdx.x, bh=blockIdx.y;
  const int tid=threadIdx.x;
  {
    const int ml=tid>>2, dg=(tid&3)*16;
    float s[16];
    #pragma unroll
    for(int e=0;e<16;e++) s[e]=0.f;
    #pragma unroll
    for(int c=0;c<4;c++){
      const float* pb = kvp + ((size_t)(c*64+bh)*256 + mt*64+ml)*64 + dg;
      #pragma unroll
      for(int e4=0;e4<4;e4++){
        f4v v = *(const f4v*)(pb + e4*4);
        #pragma unroll
        for(int j=0;j<4;j++) s[e4*4+j] += v[j];
      }
    }
    #pragma unroll
    for(int e=0;e<16;e++) tb[ml*68 + dg + e] = f2bf(s[e]);
  }
  __syncthreads();
  {
    const int dh=tid>>2, mg=(tid&3)*16;
    ushort_t* ob = kvb + (size_t)bh*16384 + (size_t)dh*256 + mt*64 + mg;
    #pragma unroll
    for(int e4=0;e4<4;e4++){
      s4v o;
      #pragma unroll
      for(int j=0;j<4;j++) o[j] = (short)tb[(mg+e4*4+j)*68 + dh];
      *(s4v*)(ob + e4*4) = o;
    }
  }
}

// ---------------- fused attention (per b,h,64 rows) ----------------
// Barrier-free: lqp rows are wave-private; ksum read per-thread from global.
// m-chunked (2 x 128) -> LDS 17.4 KB; dd[8] instead of dd[16].
__global__ __launch_bounds__(256,5) void k_attn(const ushort_t* __restrict__ qkv,
    const ushort_t* __restrict__ projS, const ushort_t* __restrict__ kvT,
    const float* __restrict__ ksum, ushort_t* __restrict__ attnW)
{
  __shared__ ushort_t lqp[64*136];   // [l][m-chunk], stride 136 (b128-read conflict-free)
  const int lt=blockIdx.x, h=blockIdx.y, b=blockIdx.z;
  const int tid=threadIdx.x, wave=tid>>6, lane=tid&63, quad=lane>>4, lid=lane&15;
  const int l0 = lt*64;
  const float* ksb = ksum + ((size_t)b*16+h)*256;
  const ushort_t* kvb = kvT + ((size_t)b*16+h)*(64*256);
  const ushort_t* qbase = qkv + (size_t)(b*4096+l0+wave*16+lid)*3072 + h*64;
  const s8v af0 = *(const s8v*)(qbase + quad*8);
  const s8v af1 = *(const s8v*)(qbase + 32 + quad*8);

  f4v num[4];
  #pragma unroll
  for(int j=0;j<4;j++){ f4v z={0.f,0.f,0.f,0.f}; num[j]=z; }
  float dnm[4] = {0.f,0.f,0.f,0.f};

  #pragma unroll
  for(int mc=0; mc<2; mc++){
    f4v dd[8];
    #pragma unroll
    for(int n=0;n<8;n++){ f4v z={0.f,0.f,0.f,0.f}; dd[n]=z; }
    #pragma unroll
    for(int n=0;n<8;n++){
      const ushort_t* pb = projS + ((mc*8+n)*16+lid)*64 + quad*8;
      s8v b0 = *(const s8v*)(pb);
      s8v b1 = *(const s8v*)(pb + 32);
      dd[n] = MFMA(af0, b0, dd[n]);
      dd[n] = MFMA(af1, b1, dd[n]);
    }
    float kse[8];
    #pragma unroll
    for(int n=0;n<8;n++) kse[n] = ksb[mc*128 + n*16 + lid];
    #pragma unroll
    for(int r=0;r<4;r++){
      const int lrow = wave*16 + quad*4 + r;
      #pragma unroll
      for(int n=0;n<8;n++){
        float e = __expf(dd[n][r]) + 1e-6f;
        dnm[r] += e * kse[n];
        lqp[lrow*136 + n*16 + lid] = f2bf(e);
      }
    }
    asm volatile("s_waitcnt lgkmcnt(0)" ::: "memory");   // writes visible to own wave
    __builtin_amdgcn_sched_barrier(0);
    #pragma unroll
    for(int ks=0;ks<4;ks++){
      s8v a = *(const s8v*)&lqp[(wave*16+lid)*136 + ks*32 + quad*8];
      #pragma unroll
      for(int j=0;j<4;j++){
        s8v bfr = *(const s8v*)(kvb + (size_t)(j*16+lid)*256 + mc*128 + ks*32 + quad*8);
        num[j] = MFMA(a, bfr, num[j]);
      }
    }
    asm volatile("s_waitcnt lgkmcnt(0)" ::: "memory");   // reads done before overwrite
    __builtin_amdgcn_sched_barrier(0);
  }
  #pragma unroll
  for(int r=0;r<4;r++){
    float s = dnm[r];
    s += __shfl_xor(s,1,64); s += __shfl_xor(s,2,64);
    s += __shfl_xor(s,4,64); s += __shfl_xor(s,8,64);
    dnm[r] = s;
  }
  #pragma unroll
  for(int j=0;j<4;j++)
    #pragma unroll
    for(int r=0;r<4;r++){
      const int row = b*4096 + l0 + wave*16 + quad*4 + r;
      attnW[(size_t)row*3072 + h*64 + j*16 + lid] = f2bf(num[j][r] / dnm[r]);
    }
}

// ---------------- LayerNorm ----------------
__device__ __forceinline__ float blockRed(float s, float* buf, int tid){
  #pragma unroll
  for(int o=1;o<64;o<<=1) s += __shfl_xor(s, o, 64);
  __syncthreads();
  if((tid&63)==0) buf[tid>>6] = s;
  __syncthreads();
  return buf[0]+buf[1]+buf[2]+buf[3];
}
template<int FINAL>
__global__ __launch_bounds__(256) void k_ln(const float* __restrict__ xres,
    const ushort_t* __restrict__ aa, int lda_a,
    const ushort_t* __restrict__ bbf, int lda_b,
    const float* __restrict__ g, const float* __restrict__ be,
    ushort_t* __restrict__ obf, int ldo, float* __restrict__ of)
{
  __shared__ float buf[4];
  const int row = blockIdx.x, tid = threadIdx.x;
  float v[4];
  if(FINAL==0){
    f4v xv = *(const f4v*)(xres + (size_t)row*1024 + tid*4);
    s4v av = *(const s4v*)(aa + (size_t)row*lda_a + tid*4);
    #pragma unroll
    for(int i=0;i<4;i++) v[i] = xv[i] + bf2f(av[i]);
  } else {
    s4v av = *(const s4v*)(aa + (size_t)row*lda_a + tid*4);
    s4v bv = *(const s4v*)(bbf + (size_t)row*lda_b + tid*4);
    #pragma unroll
    for(int i=0;i<4;i++) v[i] = bf2f(av[i]) + bf2f(bv[i]);
  }
  float s = v[0]+v[1]+v[2]+v[3];
  s = blockRed(s, buf, tid);
  const float mu = s * (1.f/1024.f);
  float q = 0.f;
  #pragma unroll
  for(int i=0;i<4;i++){ float d=v[i]-mu; q += d*d; }
  q = blockRed(q, buf, tid);
  const float rs = rsqrtf(q*(1.f/1024.f) + 1e-6f);
  const int col = tid*4;
  #pragma unroll
  for(int i=0;i<4;i++){
    float y = (v[i]-mu)*rs*g[col+i] + be[col+i];
    if(FINAL==0) obf[(size_t)row*ldo + col + i] = f2bf(y);
    else         of[(size_t)row*1024 + col + i] = y;
  }
}

// ---------------- launch ----------------
extern "C" void kernel_launch(void* const* d_in, const int* in_sizes, int n_in,
                              void* d_out, int out_size, void* d_ws, size_t ws_size,
                              hipStream_t stream) {
  (void)in_sizes; (void)n_in; (void)out_size; (void)ws_size;
  const float* x    = (const float*)d_in[0];
  const float* wq   = (const float*)d_in[1];
  const float* wk   = (const float*)d_in[2];
  const float* wv   = (const float*)d_in[3];
  const float* wo   = (const float*)d_in[4];
  const float* proj = (const float*)d_in[5];
  const float* ln1g = (const float*)d_in[6];
  const float* ln1b = (const float*)d_in[7];
  const float* ln2g = (const float*)d_in[8];
  const float* ln2b = (const float*)d_in[9];
  const float* w1   = (const float*)d_in[10];
  const float* b1   = (const float*)d_in[11];
  const float* w2   = (const float*)d_in[12];
  const float* b2   = (const float*)d_in[13];

  char* wsb = (char*)d_ws;
  size_t off = 0;
  auto alloc = [&](size_t bytes)->char*{
    char* p = wsb + off; off = (off + bytes + 255) & ~(size_t)255; return p;
  };
  ushort_t* wqkvT = (ushort_t*)alloc(3072ull*1024*2);
  ushort_t* woT   = (ushort_t*)alloc(1024ull*1024*2);
  ushort_t* w1T   = (ushort_t*)alloc(4096ull*1024*2);
  ushort_t* w2T   = (ushort_t*)alloc(1024ull*4096*2);
  ushort_t* projS = (ushort_t*)alloc(256*64*2);
  ushort_t* qkv   = (ushort_t*)alloc(16384ull*3072*2);
  size_t zoff = off;
  float*    ksumb = (float*)alloc(4ull*16*256*4);
  size_t zlen = off - zoff;
  ushort_t* kvb   = (ushort_t*)alloc(4ull*16*64*256*2);

  ushort_t* out1 = qkv;
  ushort_t* ao   = qkv + 1024;
  ushort_t* attn = qkv + 2048;
  ushort_t* ffn  = qkv + 2048;
  ushort_t* xb   = (ushort_t*)d_out;
  float*    kvp  = (float*)d_out;
  ushort_t* hb   = (ushort_t*)d_out;

  k_cvt_t<<<dim3(16,16),256,0,stream>>>(wq, wqkvT,                1024, 1024);
  k_cvt_t<<<dim3(16,16),256,0,stream>>>(wk, wqkvT + 1024ull*1024, 1024, 1024);
  k_cvt_t<<<dim3(16,16),256,0,stream>>>(wv, wqkvT + 2048ull*1024, 1024, 1024);
  k_cvt_t<<<dim3(16,16),256,0,stream>>>(wo, woT, 1024, 1024);
  k_cvt_t<<<dim3(64,16),256,0,stream>>>(w1, w1T, 4096, 1024);
  k_cvt_t<<<dim3(16,64),256,0,stream>>>(w2, w2T, 1024, 4096);
  k_proj<<<64,256,0,stream>>>(proj, projS);
  k_f2b4<<<16384,256,0,stream>>>(x, xb, 16384*1024/4);
  {
    int nz = (int)(zlen/4);
    k_zero<<<(nz+255)/256,256,0,stream>>>((float*)(wsb+zoff), nz);
  }

  // QKV projection
  gemm8<0><<<dim3(64,12),512,0,stream>>>(xb, 1024, wqkvT, 1024, qkv, 3072, nullptr, 16384, 3072, 1024);
  k_kv<<<dim3(4,4,64),256,0,stream>>>(qkv, projS, kvp, ksumb);
  k_f2bt<<<dim3(4,64),256,0,stream>>>(kvp, kvb);
  k_attn<<<dim3(64,16,4),256,0,stream>>>(qkv, projS, kvb, ksumb, attn);
  // output projection + LN1
  gemm8<0><<<dim3(64,4),512,0,stream>>>(attn, 3072, woT, 1024, ao, 3072, nullptr, 16384, 1024, 1024);
  k_ln<0><<<16384,256,0,stream>>>(x, ao, 3072, nullptr, 0, ln1g, ln1b, out1, 3072, nullptr);
  // FFN in 2 row-chunks of 8192
  for(int c=0;c<2;c++){
    const size_t ro = (size_t)c*8192*3072;
    gemm8<2><<<dim3(32,16),512,0,stream>>>(out1 + ro, 3072, w1T, 1024, hb, 4096, b1, 8192, 4096, 1024);
    gemm8<1><<<dim3(32,4),512,0,stream>>>(hb, 4096, w2T, 4096, ffn + ro, 3072, b2, 8192, 1024, 4096);
  }
  k_ln<1><<<16384,256,0,stream>>>(nullptr, out1, 3072, ffn, 3072, ln2g, ln2b, nullptr, 0, (float*)d_out);
}

// Round 4
// 856.425 us; speedup vs baseline: 1.2592x; 1.0773x over previous
//
#include <hip/hip_runtime.h>

typedef unsigned short ushort_t;
typedef unsigned int uint_t;
typedef __attribute__((ext_vector_type(8))) short s8v;
typedef __attribute__((ext_vector_type(4))) short s4v;
typedef __attribute__((ext_vector_type(4))) float f4v;

#define MFMA(a,b,c) __builtin_amdgcn_mfma_f32_16x16x32_bf16(a,b,c,0,0,0)

#define GLDS16(g, l) \
  __builtin_amdgcn_global_load_lds((const __attribute__((address_space(1))) void*)(g), \
                                   (__attribute__((address_space(3))) void*)(l), 16, 0, 0)

__device__ __forceinline__ float bf2f(short s){
  return __uint_as_float(((uint_t)(ushort_t)s) << 16);
}
__device__ __forceinline__ ushort_t f2bf(float f){
  uint_t u = __float_as_uint(f);
  u += 0x7fffu + ((u >> 16) & 1u);
  return (ushort_t)(u >> 16);
}

// ---------------- conversions ----------------
__global__ __launch_bounds__(256) void k_cvt_t(const float* __restrict__ src,
    ushort_t* __restrict__ dst, int R, int C){
  __shared__ ushort_t t[64*68];
  const int r0 = blockIdx.x*64, c0 = blockIdx.y*64;
  const int tid = threadIdx.x;
  const int cl = tid>>4, rl4 = (tid&15)*4;
  #pragma unroll
  for(int cc=0; cc<64; cc+=16){
    f4v v = *(const f4v*)(src + (size_t)(c0+cl+cc)*R + r0 + rl4);
    #pragma unroll
    for(int j=0;j<4;j++) t[(rl4+j)*68 + cl+cc] = f2bf(v[j]);
  }
  __syncthreads();
  const int rw = tid>>4, cw4 = (tid&15)*4;
  #pragma unroll
  for(int rr=0; rr<64; rr+=16){
    s4v o;
    #pragma unroll
    for(int j=0;j<4;j++) o[j] = (short)t[(rw+rr)*68 + cw4 + j];
    *(s4v*)(dst + (size_t)(r0+rw+rr)*C + c0 + cw4) = o;
  }
}
__global__ __launch_bounds__(256) void k_proj(const float* __restrict__ src,
    ushort_t* __restrict__ dst){
  int i = blockIdx.x*256 + threadIdx.x;
  if(i < 256*64) dst[i] = f2bf(src[i] * 0.3535533905932738f);
}
__global__ __launch_bounds__(256) void k_f2b4(const float* __restrict__ s,
    ushort_t* __restrict__ d, int n4){
  int i = blockIdx.x*256 + threadIdx.x;
  if(i < n4){
    f4v v = ((const f4v*)s)[i];
    s4v o;
    #pragma unroll
    for(int j=0;j<4;j++) o[j] = (short)f2bf(v[j]);
    ((s4v*)d)[i] = o;
  }
}
__global__ __launch_bounds__(256) void k_zero(float* __restrict__ p, int n){
  int i = blockIdx.x*256 + threadIdx.x;
  if(i < n) p[i] = 0.f;
}

// ============ 256x256 8-phase bf16 GEMM: C[M][N] = A[M][K] * Bt[N][K]^T ============
template<int MODE>
__global__ __launch_bounds__(512,2) void gemm8(const ushort_t* __restrict__ A, int lda,
    const ushort_t* __restrict__ Bt, int ldb, ushort_t* __restrict__ Cc, int ldc,
    const float* __restrict__ bias, int M, int N, int K)
{
  __shared__ ushort_t lsh[4][256*64];   // [buf*2+isB][row*64 + k]
  const int tid = threadIdx.x;
  const int wave = tid>>6, lane = tid&63, quad = lane>>4, lid = lane&15;
  const int wm = wave>>2, wn = wave&3;
  const int nwgx = gridDim.x;
  const int nwg  = nwgx * gridDim.y;
  const int orig = blockIdx.y*nwgx + blockIdx.x;
  const int swz  = (orig&7)*(nwg>>3) + (orig>>3);
  const int row0 = (swz % nwgx)*256, col0 = (swz / nwgx)*256;

  const int srow = lane>>3;
  const int scol = ((lane&7) ^ srow)*8;
  const ushort_t* gA = A  + (size_t)(row0 + wave*8 + srow)*lda + scol;
  const ushort_t* gB = Bt + (size_t)(col0 + wave*8 + srow)*ldb + scol;
  const int ldsw = wave*512;

  const int aoff = (wm*128 + lid)*64;
  const int boff = (wn*64  + lid)*64;
  const int k0s  = (quad*8)        ^ ((lid&7)<<3);
  const int k1s  = (32 + quad*8)   ^ ((lid&7)<<3);

  f4v acc[8][4];
  #pragma unroll
  for(int m=0;m<8;m++)
    #pragma unroll
    for(int n=0;n<4;n++){ f4v z={0.f,0.f,0.f,0.f}; acc[m][n]=z; }
  s8v af[4][2], bf[4][2];

  const int KT = K>>6;
  const int NP = KT>>1;

#define STG(buf, isB, half, kt) do{ \
    const ushort_t* _g = ((isB)? gB : gA) + (size_t)((half)*128)*((isB)? ldb : lda) + (size_t)(kt)*64; \
    GLDS16(_g, &lsh[(buf)*2+(isB)][(half)*8192 + ldsw]); \
    GLDS16(_g + (size_t)64*((isB)? ldb : lda), &lsh[(buf)*2+(isB)][(half)*8192 + 4096 + ldsw]); \
  }while(0)

#define DSA(buf, mh) do{ \
    const ushort_t* _l = &lsh[(buf)*2][aoff + (mh)*4096]; \
    _Pragma("unroll") \
    for(int _m=0;_m<4;_m++){ \
      af[_m][0] = *(const s8v*)(_l + _m*1024 + k0s); \
      af[_m][1] = *(const s8v*)(_l + _m*1024 + k1s); \
    } \
  }while(0)

#define DSB(buf, nh) do{ \
    const ushort_t* _l = &lsh[(buf)*2+1][boff]; \
    _Pragma("unroll") \
    for(int _n=0;_n<2;_n++){ \
      bf[(nh)*2+_n][0] = *(const s8v*)(_l + ((nh)*2+_n)*1024 + k0s); \
      bf[(nh)*2+_n][1] = *(const s8v*)(_l + ((nh)*2+_n)*1024 + k1s); \
    } \
  }while(0)

#define MMP(mh, nh) do{ \
    __builtin_amdgcn_s_setprio(1); \
    _Pragma("unroll") \
    for(int _m=0;_m<4;_m++) \
      _Pragma("unroll") \
      for(int _n=0;_n<2;_n++){ \
        acc[(mh)*4+_m][(nh)*2+_n] = MFMA(af[_m][0], bf[(nh)*2+_n][0], acc[(mh)*4+_m][(nh)*2+_n]); \
        acc[(mh)*4+_m][(nh)*2+_n] = MFMA(af[_m][1], bf[(nh)*2+_n][1], acc[(mh)*4+_m][(nh)*2+_n]); \
      } \
    __builtin_amdgcn_s_setprio(0); \
  }while(0)

#define BARX  __builtin_amdgcn_s_barrier()
#define LGKM0 do{ asm volatile("s_waitcnt lgkmcnt(0)" ::: "memory"); __builtin_amdgcn_sched_barrier(0); }while(0)
#define VM2   do{ asm volatile("s_waitcnt vmcnt(2)"   ::: "memory"); __builtin_amdgcn_sched_barrier(0); }while(0)

  STG(0,0,0,0); STG(0,0,1,0); STG(0,1,0,0); STG(0,1,1,0);
  STG(1,0,0,1);
  VM2;
  BARX;

  for(int p=0; p<NP; p++){
    const int t1 = 2*p+1;
    const int t2 = (2*p+2 < KT)? 2*p+2 : KT-1;
    const int t3 = (2*p+3 < KT)? 2*p+3 : KT-1;
    DSA(0,0); DSB(0,0); STG(1,0,1,t1);
    asm volatile("s_waitcnt lgkmcnt(8)" ::: "memory");
    BARX; LGKM0; MMP(0,0); BARX;
    DSB(0,1); STG(1,1,0,t1); STG(1,1,1,t1);
    BARX; LGKM0; MMP(0,1); BARX;
    DSA(0,1); STG(0,0,0,t2);
    BARX; LGKM0; MMP(1,0); BARX;
    MMP(1,1); VM2; BARX;
    DSA(1,0); DSB(1,0); STG(0,0,1,t2);
    asm volatile("s_waitcnt lgkmcnt(8)" ::: "memory");
    BARX; LGKM0; MMP(0,0); BARX;
    DSB(1,1); STG(0,1,0,t2); STG(0,1,1,t2);
    BARX; LGKM0; MMP(0,1); BARX;
    DSA(1,1); STG(1,0,0,t3);
    BARX; LGKM0; MMP(1,0); BARX;
    MMP(1,1); VM2; BARX;
  }
  asm volatile("s_waitcnt vmcnt(0)" ::: "memory");

  #pragma unroll
  for(int m=0;m<8;m++){
    const int row = row0 + wm*128 + (m>>2)*64 + (m&3)*16 + quad*4;
    #pragma unroll
    for(int n=0;n<4;n++){
      const int col = col0 + wn*64 + n*16 + lid;
      float bv = 0.f;
      if(MODE>=1) bv = bias[col];
      #pragma unroll
      for(int r=0;r<4;r++){
        float v = acc[m][n][r] + bv;
        if(MODE==2) v = v>0.f ? v : expm1f(v);
        Cc[(size_t)(row+r)*ldc + col] = f2bf(v);
      }
    }
  }
#undef STG
#undef DSA
#undef DSB
#undef MMP
#undef BARX
#undef LGKM0
#undef VM2
}

// ---------------- kv^T partials + ksum ----------------
__global__ __launch_bounds__(256) void k_kv(const ushort_t* __restrict__ qkv,
    const ushort_t* __restrict__ projS,
    float* __restrict__ kvp, float* __restrict__ ksum)
{
  __shared__ ushort_t lK[64*64];
  __shared__ ushort_t lvT[2][64*72];
  __shared__ ushort_t lkp[64*72];
  const int chunk=blockIdx.x, mt=blockIdx.y, bh=blockIdx.z;
  const int h=bh&15, b=bh>>4;
  const int tid=threadIdx.x, wave=tid>>6, lane=tid&63, quad=lane>>4, lid=lane&15;

  s8v pf[4][2];
  {
    const ushort_t* projM = projS + mt*64*64;
    #pragma unroll
    for(int n=0;n<4;n++)
      #pragma unroll
      for(int ks=0;ks<2;ks++)
        pf[n][ks] = *(const s8v*)(projM + (n*16+lid)*64 + ks*32 + quad*8);
  }
  f4v kvacc[4];
  #pragma unroll
  for(int j=0;j<4;j++){ f4v z={0.f,0.f,0.f,0.f}; kvacc[j]=z; }
  float ksacc[4] = {};

  const int sl = tid>>3;
  const int gcb = (tid&7) ^ (sl&7);
  const size_t lbase = (size_t)(b*4096 + chunk*1024);
  const ushort_t* gK0 = qkv + (lbase + sl     )*3072 + 1024 + h*64 + gcb*8;
  const ushort_t* gK1 = qkv + (lbase + sl + 32)*3072 + 1024 + h*64 + gcb*8;
  ushort_t* lK0 = &lK[(wave*8     )*64];
  ushort_t* lK1 = &lK[(wave*8 + 32)*64];
  const ushort_t* gV = qkv + (lbase + lane)*3072 + 2048 + h*64 + wave*16;

  for(int it=0; it<16; it++){
    const int p = it&1;
    GLDS16(gK0, lK0);
    GLDS16(gK1, lK1);
    {
      s8v v0 = *(const s8v*)gV;
      s8v v1 = *(const s8v*)(gV + 8);
      #pragma unroll
      for(int jj=0;jj<8;jj++){
        lvT[p][(wave*16+jj  )*72 + lane] = (ushort_t)v0[jj];
        lvT[p][(wave*16+8+jj)*72 + lane] = (ushort_t)v1[jj];
      }
    }
    gK0 += 64*3072; gK1 += 64*3072; gV += 64*3072;
    __syncthreads();
    float dv;
    {
      const int rl = wave*16 + (lane>>2);
      const int cb0 = 2*(lane&3);
      s8v u0 = *(const s8v*)&lK[rl*64 + ((cb0  )^(rl&7))*8];
      s8v u1 = *(const s8v*)&lK[rl*64 + ((cb0+1)^(rl&7))*8];
      float s = 0.f;
      #pragma unroll
      for(int jj=0;jj<8;jj++){
        float f0=bf2f(u0[jj]), f1=bf2f(u1[jj]);
        s += f0*f0 + f1*f1;
      }
      s += __shfl_xor(s,1,64); s += __shfl_xor(s,2,64);
      dv = s*(1.f/16.f);
    }
    f4v dd[4];
    #pragma unroll
    for(int n=0;n<4;n++){ f4v z={0.f,0.f,0.f,0.f}; dd[n]=z; }
    {
      const int ra = wave*16 + lid;
      #pragma unroll
      for(int ks=0;ks<2;ks++){
        s8v af = *(const s8v*)&lK[ra*64 + ((ks*4+quad)^(ra&7))*8];
        #pragma unroll
        for(int n=0;n<4;n++) dd[n] = MFMA(af, pf[n][ks], dd[n]);
      }
    }
    const int lrb = wave*16 + quad*4;
    #pragma unroll
    for(int n=0;n<4;n++){
      s4v pk;
      #pragma unroll
      for(int r=0;r<4;r++){
        float dg = __shfl(dv, (quad*4+r)*4, 64);
        float ekp = __expf(dd[n][r] - dg) + 1e-6f;
        ksacc[n] += ekp;
        pk[r] = (short)f2bf(ekp);
      }
      *(s4v*)&lkp[(n*16+lid)*72 + lrb] = pk;
    }
    __syncthreads();
    #pragma unroll
    for(int ks=0;ks<2;ks++){
      s8v af = *(const s8v*)&lkp[(wave*16+lid)*72 + ks*32 + quad*8];
      #pragma unroll
      for(int j=0;j<4;j++){
        s8v bfr = *(const s8v*)&lvT[p][(j*16+lid)*72 + ks*32 + quad*8];
        kvacc[j] = MFMA(af, bfr, kvacc[j]);
      }
    }
  }
  #pragma unroll
  for(int n=0;n<4;n++){
    float s = ksacc[n];
    s += __shfl_xor(s,16,64); s += __shfl_xor(s,32,64);
    if(quad==0) atomicAdd(&ksum[((size_t)b*16+h)*256 + mt*64 + n*16 + lid], s);
  }
  float* kvo = kvp + ((size_t)chunk*64 + bh)*16384;
  #pragma unroll
  for(int j=0;j<4;j++)
    #pragma unroll
    for(int r=0;r<4;r++)
      kvo[(mt*64 + wave*16 + quad*4 + r)*64 + j*16 + lid] = kvacc[j][r];
}

// ---------------- reduce 4 kv partials + transpose to bf16 [dh][m] ----------------
__global__ __launch_bounds__(256) void k_f2bt(const float* __restrict__ kvp,
    ushort_t* __restrict__ kvb)
{
  __shared__ ushort_t tb[64*68];
  const int mt=blockIdx.x, bh=blockIdx.y;
  const int tid=threadIdx.x;
  {
    const int ml=tid>>2, dg=(tid&3)*16;
    float s[16];
    #pragma unroll
    for(int e=0;e<16;e++) s[e]=0.f;
    #pragma unroll
    for(int c=0;c<4;c++){
      const float* pb = kvp + ((size_t)(c*64+bh)*256 + mt*64+ml)*64 + dg;
      #pragma unroll
      for(int e4=0;e4<4;e4++){
        f4v v = *(const f4v*)(pb + e4*4);
        #pragma unroll
        for(int j=0;j<4;j++) s[e4*4+j] += v[j];
      }
    }
    #pragma unroll
    for(int e=0;e<16;e++) tb[ml*68 + dg + e] = f2bf(s[e]);
  }
  __syncthreads();
  {
    const int dh=tid>>2, mg=(tid&3)*16;
    ushort_t* ob = kvb + (size_t)bh*16384 + (size_t)dh*256 + mt*64 + mg;
    #pragma unroll
    for(int e4=0;e4<4;e4++){
      s4v o;
      #pragma unroll
      for(int j=0;j<4;j++) o[j] = (short)tb[(mg+e4*4+j)*68 + dh];
      *(s4v*)(ob + e4*4) = o;
    }
  }
}

// ---------------- fused attention (per b,h,128 rows) ----------------
// kvb bulk-staged into LDS via global_load_lds (XOR-swizzled source, linear dest,
// same XOR on ds_read -> conflict-free). 2 row-tiles of 64 per block amortize
// staging + ksum. lqp rows wave-private; single __syncthreads (drains staging).
__global__ __launch_bounds__(256,3) void k_attn(const ushort_t* __restrict__ qkv,
    const ushort_t* __restrict__ projS, const ushort_t* __restrict__ kvT,
    const float* __restrict__ ksum, ushort_t* __restrict__ attnW)
{
  __shared__ ushort_t lkv[64*256];   // [dh][m], col-blocks XOR-swizzled by dh&7
  __shared__ ushort_t lqp[64*136];   // [l][m-chunk], stride 136
  const int lt=blockIdx.x, h=blockIdx.y, b=blockIdx.z;
  const int tid=threadIdx.x, wave=tid>>6, lane=tid&63, quad=lane>>4, lid=lane&15;
  const ushort_t* kvbG = kvT + ((size_t)b*16+h)*(64*256);
  const float* ksb = ksum + ((size_t)b*16+h)*256;
  float kse[16];
  #pragma unroll
  for(int n=0;n<16;n++) kse[n] = ksb[n*16+lid];
  const int sdh = tid>>5;            // staging: row-in-group 0..7
  const int scb = tid&31;            // staging: 8-elem col-block

  #pragma unroll
  for(int t=0;t<2;t++){
    const int l0 = lt*128 + t*64;
    const ushort_t* qbase = qkv + (size_t)(b*4096+l0+wave*16+lid)*3072 + h*64;
    const s8v af0 = *(const s8v*)(qbase + quad*8);
    const s8v af1 = *(const s8v*)(qbase + 32 + quad*8);
    f4v num[4];
    #pragma unroll
    for(int j=0;j<4;j++){ f4v z={0.f,0.f,0.f,0.f}; num[j]=z; }
    float dnm[4] = {0.f,0.f,0.f,0.f};

    #pragma unroll
    for(int mc=0; mc<2; mc++){
      f4v dd[8];
      #pragma unroll
      for(int n=0;n<8;n++){ f4v z={0.f,0.f,0.f,0.f}; dd[n]=z; }
      #pragma unroll
      for(int n=0;n<8;n++){
        const ushort_t* pb = projS + ((mc*8+n)*16+lid)*64 + quad*8;
        s8v b0 = *(const s8v*)(pb);
        s8v b1 = *(const s8v*)(pb + 32);
        dd[n] = MFMA(af0, b0, dd[n]);
        dd[n] = MFMA(af1, b1, dd[n]);
      }
      if(t==0 && mc==0){
        // issue kvb staging AFTER projS loads (vmcnt is in-order: keeps projS
        // consumption from waiting on the DMA); overlaps exp phase below.
        __builtin_amdgcn_sched_barrier(0);
        #pragma unroll
        for(int q=0;q<8;q++){
          const int dh = q*8 + sdh;
          GLDS16(kvbG + dh*256 + ((scb ^ (dh&7))*8),
                 &lkv[(size_t)(q*8 + wave*2)*256]);
        }
        __builtin_amdgcn_sched_barrier(0);
      }
      #pragma unroll
      for(int r=0;r<4;r++){
        const int lrow = wave*16 + quad*4 + r;
        #pragma unroll
        for(int n=0;n<8;n++){
          float e = __expf(dd[n][r]) + 1e-6f;
          dnm[r] += e * kse[mc*8+n];
          lqp[lrow*136 + n*16 + lid] = f2bf(e);
        }
      }
      if(t==0 && mc==0){
        asm volatile("s_waitcnt vmcnt(0)" ::: "memory");
        __syncthreads();                 // kvb staged everywhere + own lqp drained
      } else {
        asm volatile("s_waitcnt lgkmcnt(0)" ::: "memory");
        __builtin_amdgcn_sched_barrier(0);
      }
      #pragma unroll
      for(int ks=0;ks<4;ks++){
        s8v a = *(const s8v*)&lqp[(wave*16+lid)*136 + ks*32 + quad*8];
        #pragma unroll
        for(int j=0;j<4;j++){
          const int cbr = mc*16 + ks*4 + quad;
          s8v bfr = *(const s8v*)&lkv[(size_t)(j*16+lid)*256 + ((cbr ^ (lid&7))*8)];
          num[j] = MFMA(a, bfr, num[j]);
        }
      }
      asm volatile("s_waitcnt lgkmcnt(0)" ::: "memory");   // lqp reads done before overwrite
      __builtin_amdgcn_sched_barrier(0);
    }
    #pragma unroll
    for(int r=0;r<4;r++){
      float s = dnm[r];
      s += __shfl_xor(s,1,64); s += __shfl_xor(s,2,64);
      s += __shfl_xor(s,4,64); s += __shfl_xor(s,8,64);
      dnm[r] = s;
    }
    #pragma unroll
    for(int j=0;j<4;j++)
      #pragma unroll
      for(int r=0;r<4;r++){
        const int row = b*4096 + l0 + wave*16 + quad*4 + r;
        attnW[(size_t)row*3072 + h*64 + j*16 + lid] = f2bf(num[j][r] / dnm[r]);
      }
  }
}

// ---------------- LayerNorm ----------------
__device__ __forceinline__ float blockRed(float s, float* buf, int tid){
  #pragma unroll
  for(int o=1;o<64;o<<=1) s += __shfl_xor(s, o, 64);
  __syncthreads();
  if((tid&63)==0) buf[tid>>6] = s;
  __syncthreads();
  return buf[0]+buf[1]+buf[2]+buf[3];
}
template<int FINAL>
__global__ __launch_bounds__(256) void k_ln(const float* __restrict__ xres,
    const ushort_t* __restrict__ aa, int lda_a,
    const ushort_t* __restrict__ bbf, int lda_b,
    const float* __restrict__ g, const float* __restrict__ be,
    ushort_t* __restrict__ obf, int ldo, float* __restrict__ of)
{
  __shared__ float buf[4];
  const int row = blockIdx.x, tid = threadIdx.x;
  float v[4];
  if(FINAL==0){
    f4v xv = *(const f4v*)(xres + (size_t)row*1024 + tid*4);
    s4v av = *(const s4v*)(aa + (size_t)row*lda_a + tid*4);
    #pragma unroll
    for(int i=0;i<4;i++) v[i] = xv[i] + bf2f(av[i]);
  } else {
    s4v av = *(const s4v*)(aa + (size_t)row*lda_a + tid*4);
    s4v bv = *(const s4v*)(bbf + (size_t)row*lda_b + tid*4);
    #pragma unroll
    for(int i=0;i<4;i++) v[i] = bf2f(av[i]) + bf2f(bv[i]);
  }
  float s = v[0]+v[1]+v[2]+v[3];
  s = blockRed(s, buf, tid);
  const float mu = s * (1.f/1024.f);
  float q = 0.f;
  #pragma unroll
  for(int i=0;i<4;i++){ float d=v[i]-mu; q += d*d; }
  q = blockRed(q, buf, tid);
  const float rs = rsqrtf(q*(1.f/1024.f) + 1e-6f);
  const int col = tid*4;
  #pragma unroll
  for(int i=0;i<4;i++){
    float y = (v[i]-mu)*rs*g[col+i] + be[col+i];
    if(FINAL==0) obf[(size_t)row*ldo + col + i] = f2bf(y);
    else         of[(size_t)row*1024 + col + i] = y;
  }
}

// ---------------- launch ----------------
extern "C" void kernel_launch(void* const* d_in, const int* in_sizes, int n_in,
                              void* d_out, int out_size, void* d_ws, size_t ws_size,
                              hipStream_t stream) {
  (void)in_sizes; (void)n_in; (void)out_size; (void)ws_size;
  const float* x    = (const float*)d_in[0];
  const float* wq   = (const float*)d_in[1];
  const float* wk   = (const float*)d_in[2];
  const float* wv   = (const float*)d_in[3];
  const float* wo   = (const float*)d_in[4];
  const float* proj = (const float*)d_in[5];
  const float* ln1g = (const float*)d_in[6];
  const float* ln1b = (const float*)d_in[7];
  const float* ln2g = (const float*)d_in[8];
  const float* ln2b = (const float*)d_in[9];
  const float* w1   = (const float*)d_in[10];
  const float* b1   = (const float*)d_in[11];
  const float* w2   = (const float*)d_in[12];
  const float* b2   = (const float*)d_in[13];

  char* wsb = (char*)d_ws;
  size_t off = 0;
  auto alloc = [&](size_t bytes)->char*{
    char* p = wsb + off; off = (off + bytes + 255) & ~(size_t)255; return p;
  };
  ushort_t* wqkvT = (ushort_t*)alloc(3072ull*1024*2);
  ushort_t* woT   = (ushort_t*)alloc(1024ull*1024*2);
  ushort_t* w1T   = (ushort_t*)alloc(4096ull*1024*2);
  ushort_t* w2T   = (ushort_t*)alloc(1024ull*4096*2);
  ushort_t* projS = (ushort_t*)alloc(256*64*2);
  ushort_t* qkv   = (ushort_t*)alloc(16384ull*3072*2);
  size_t zoff = off;
  float*    ksumb = (float*)alloc(4ull*16*256*4);
  size_t zlen = off - zoff;
  ushort_t* kvb   = (ushort_t*)alloc(4ull*16*64*256*2);

  ushort_t* out1 = qkv;
  ushort_t* ao   = qkv + 1024;
  ushort_t* attn = qkv + 2048;
  ushort_t* ffn  = qkv + 2048;
  ushort_t* xb   = (ushort_t*)d_out;
  float*    kvp  = (float*)d_out;
  ushort_t* hb   = (ushort_t*)d_out;

  k_cvt_t<<<dim3(16,16),256,0,stream>>>(wq, wqkvT,                1024, 1024);
  k_cvt_t<<<dim3(16,16),256,0,stream>>>(wk, wqkvT + 1024ull*1024, 1024, 1024);
  k_cvt_t<<<dim3(16,16),256,0,stream>>>(wv, wqkvT + 2048ull*1024, 1024, 1024);
  k_cvt_t<<<dim3(16,16),256,0,stream>>>(wo, woT, 1024, 1024);
  k_cvt_t<<<dim3(64,16),256,0,stream>>>(w1, w1T, 4096, 1024);
  k_cvt_t<<<dim3(16,64),256,0,stream>>>(w2, w2T, 1024, 4096);
  k_proj<<<64,256,0,stream>>>(proj, projS);
  k_f2b4<<<16384,256,0,stream>>>(x, xb, 16384*1024/4);
  {
    int nz = (int)(zlen/4);
    k_zero<<<(nz+255)/256,256,0,stream>>>((float*)(wsb+zoff), nz);
  }

  // QKV projection
  gemm8<0><<<dim3(64,12),512,0,stream>>>(xb, 1024, wqkvT, 1024, qkv, 3072, nullptr, 16384, 3072, 1024);
  k_kv<<<dim3(4,4,64),256,0,stream>>>(qkv, projS, kvp, ksumb);
  k_f2bt<<<dim3(4,64),256,0,stream>>>(kvp, kvb);
  k_attn<<<dim3(32,16,4),256,0,stream>>>(qkv, projS, kvb, ksumb, attn);
  // output projection + LN1
  gemm8<0><<<dim3(64,4),512,0,stream>>>(attn, 3072, woT, 1024, ao, 3072, nullptr, 16384, 1024, 1024);
  k_ln<0><<<16384,256,0,stream>>>(x, ao, 3072, nullptr, 0, ln1g, ln1b, out1, 3072, nullptr);
  // FFN in 2 row-chunks of 8192
  for(int c=0;c<2;c++){
    const size_t ro = (size_t)c*8192*3072;
    gemm8<2><<<dim3(32,16),512,0,stream>>>(out1 + ro, 3072, w1T, 1024, hb, 4096, b1, 8192, 4096, 1024);
    gemm8<1><<<dim3(32,4),512,0,stream>>>(hb, 4096, w2T, 4096, ffn + ro, 3072, b2, 8192, 1024, 4096);
  }
  k_ln<1><<<16384,256,0,stream>>>(nullptr, out1, 3072, ffn, 3072, ln2g, ln2b, nullptr, 0, (float*)d_out);
}

// Round 5
// 784.676 us; speedup vs baseline: 1.3743x; 1.0914x over previous
//
#include <hip/hip_runtime.h>

typedef unsigned short ushort_t;
typedef unsigned int uint_t;
typedef __attribute__((ext_vector_type(8))) short s8v;
typedef __attribute__((ext_vector_type(4))) short s4v;
typedef __attribute__((ext_vector_type(4))) float f4v;

#define MFMA(a,b,c) __builtin_amdgcn_mfma_f32_16x16x32_bf16(a,b,c,0,0,0)

#define GLDS16(g, l) \
  __builtin_amdgcn_global_load_lds((const __attribute__((address_space(1))) void*)(g), \
                                   (__attribute__((address_space(3))) void*)(l), 16, 0, 0)

__device__ __forceinline__ float bf2f(short s){
  return __uint_as_float(((uint_t)(ushort_t)s) << 16);
}
__device__ __forceinline__ ushort_t f2bf(float f){
  uint_t u = __float_as_uint(f);
  u += 0x7fffu + ((u >> 16) & 1u);
  return (ushort_t)(u >> 16);
}

// ---------------- conversions ----------------
__global__ __launch_bounds__(256) void k_cvt_t(const float* __restrict__ src,
    ushort_t* __restrict__ dst, int R, int C){
  __shared__ ushort_t t[64*68];
  const int r0 = blockIdx.x*64, c0 = blockIdx.y*64;
  const int tid = threadIdx.x;
  const int cl = tid>>4, rl4 = (tid&15)*4;
  #pragma unroll
  for(int cc=0; cc<64; cc+=16){
    f4v v = *(const f4v*)(src + (size_t)(c0+cl+cc)*R + r0 + rl4);
    #pragma unroll
    for(int j=0;j<4;j++) t[(rl4+j)*68 + cl+cc] = f2bf(v[j]);
  }
  __syncthreads();
  const int rw = tid>>4, cw4 = (tid&15)*4;
  #pragma unroll
  for(int rr=0; rr<64; rr+=16){
    s4v o;
    #pragma unroll
    for(int j=0;j<4;j++) o[j] = (short)t[(rw+rr)*68 + cw4 + j];
    *(s4v*)(dst + (size_t)(r0+rw+rr)*C + c0 + cw4) = o;
  }
}
__global__ __launch_bounds__(256) void k_proj(const float* __restrict__ src,
    ushort_t* __restrict__ dst){
  int i = blockIdx.x*256 + threadIdx.x;
  if(i < 256*64) dst[i] = f2bf(src[i] * 0.3535533905932738f);
}
__global__ __launch_bounds__(256) void k_f2b4(const float* __restrict__ s,
    ushort_t* __restrict__ d, int n4){
  int i = blockIdx.x*256 + threadIdx.x;
  if(i < n4){
    f4v v = ((const f4v*)s)[i];
    s4v o;
    #pragma unroll
    for(int j=0;j<4;j++) o[j] = (short)f2bf(v[j]);
    ((s4v*)d)[i] = o;
  }
}
__global__ __launch_bounds__(256) void k_zero(float* __restrict__ p, int n){
  int i = blockIdx.x*256 + threadIdx.x;
  if(i < n) p[i] = 0.f;
}

// ============ 256x256 8-phase bf16 GEMM: C[M][N] = A[M][K] * Bt[N][K]^T ============
template<int MODE>
__global__ __launch_bounds__(512,2) void gemm8(const ushort_t* __restrict__ A, int lda,
    const ushort_t* __restrict__ Bt, int ldb, ushort_t* __restrict__ Cc, int ldc,
    const float* __restrict__ bias, int M, int N, int K)
{
  __shared__ ushort_t lsh[4][256*64];   // [buf*2+isB][row*64 + k]
  const int tid = threadIdx.x;
  const int wave = tid>>6, lane = tid&63, quad = lane>>4, lid = lane&15;
  const int wm = wave>>2, wn = wave&3;
  const int nwgx = gridDim.x;
  const int nwg  = nwgx * gridDim.y;
  const int orig = blockIdx.y*nwgx + blockIdx.x;
  const int swz  = (orig&7)*(nwg>>3) + (orig>>3);
  const int row0 = (swz % nwgx)*256, col0 = (swz / nwgx)*256;

  const int srow = lane>>3;
  const int scol = ((lane&7) ^ srow)*8;
  const ushort_t* gA = A  + (size_t)(row0 + wave*8 + srow)*lda + scol;
  const ushort_t* gB = Bt + (size_t)(col0 + wave*8 + srow)*ldb + scol;
  const int ldsw = wave*512;

  const int aoff = (wm*128 + lid)*64;
  const int boff = (wn*64  + lid)*64;
  const int k0s  = (quad*8)        ^ ((lid&7)<<3);
  const int k1s  = (32 + quad*8)   ^ ((lid&7)<<3);

  f4v acc[8][4];
  #pragma unroll
  for(int m=0;m<8;m++)
    #pragma unroll
    for(int n=0;n<4;n++){ f4v z={0.f,0.f,0.f,0.f}; acc[m][n]=z; }
  s8v af[4][2], bf[4][2];

  const int KT = K>>6;
  const int NP = KT>>1;

#define STG(buf, isB, half, kt) do{ \
    const ushort_t* _g = ((isB)? gB : gA) + (size_t)((half)*128)*((isB)? ldb : lda) + (size_t)(kt)*64; \
    GLDS16(_g, &lsh[(buf)*2+(isB)][(half)*8192 + ldsw]); \
    GLDS16(_g + (size_t)64*((isB)? ldb : lda), &lsh[(buf)*2+(isB)][(half)*8192 + 4096 + ldsw]); \
  }while(0)

#define DSA(buf, mh) do{ \
    const ushort_t* _l = &lsh[(buf)*2][aoff + (mh)*4096]; \
    _Pragma("unroll") \
    for(int _m=0;_m<4;_m++){ \
      af[_m][0] = *(const s8v*)(_l + _m*1024 + k0s); \
      af[_m][1] = *(const s8v*)(_l + _m*1024 + k1s); \
    } \
  }while(0)

#define DSB(buf, nh) do{ \
    const ushort_t* _l = &lsh[(buf)*2+1][boff]; \
    _Pragma("unroll") \
    for(int _n=0;_n<2;_n++){ \
      bf[(nh)*2+_n][0] = *(const s8v*)(_l + ((nh)*2+_n)*1024 + k0s); \
      bf[(nh)*2+_n][1] = *(const s8v*)(_l + ((nh)*2+_n)*1024 + k1s); \
    } \
  }while(0)

#define MMP(mh, nh) do{ \
    __builtin_amdgcn_s_setprio(1); \
    _Pragma("unroll") \
    for(int _m=0;_m<4;_m++) \
      _Pragma("unroll") \
      for(int _n=0;_n<2;_n++){ \
        acc[(mh)*4+_m][(nh)*2+_n] = MFMA(af[_m][0], bf[(nh)*2+_n][0], acc[(mh)*4+_m][(nh)*2+_n]); \
        acc[(mh)*4+_m][(nh)*2+_n] = MFMA(af[_m][1], bf[(nh)*2+_n][1], acc[(mh)*4+_m][(nh)*2+_n]); \
      } \
    __builtin_amdgcn_s_setprio(0); \
  }while(0)

#define BARX  __builtin_amdgcn_s_barrier()
#define LGKM0 do{ asm volatile("s_waitcnt lgkmcnt(0)" ::: "memory"); __builtin_amdgcn_sched_barrier(0); }while(0)
#define VM2   do{ asm volatile("s_waitcnt vmcnt(2)"   ::: "memory"); __builtin_amdgcn_sched_barrier(0); }while(0)

  STG(0,0,0,0); STG(0,0,1,0); STG(0,1,0,0); STG(0,1,1,0);
  STG(1,0,0,1);
  VM2;
  BARX;

  for(int p=0; p<NP; p++){
    const int t1 = 2*p+1;
    const int t2 = (2*p+2 < KT)? 2*p+2 : KT-1;
    const int t3 = (2*p+3 < KT)? 2*p+3 : KT-1;
    DSA(0,0); DSB(0,0); STG(1,0,1,t1);
    asm volatile("s_waitcnt lgkmcnt(8)" ::: "memory");
    BARX; LGKM0; MMP(0,0); BARX;
    DSB(0,1); STG(1,1,0,t1); STG(1,1,1,t1);
    BARX; LGKM0; MMP(0,1); BARX;
    DSA(0,1); STG(0,0,0,t2);
    BARX; LGKM0; MMP(1,0); BARX;
    MMP(1,1); VM2; BARX;
    DSA(1,0); DSB(1,0); STG(0,0,1,t2);
    asm volatile("s_waitcnt lgkmcnt(8)" ::: "memory");
    BARX; LGKM0; MMP(0,0); BARX;
    DSB(1,1); STG(0,1,0,t2); STG(0,1,1,t2);
    BARX; LGKM0; MMP(0,1); BARX;
    DSA(1,1); STG(1,0,0,t3);
    BARX; LGKM0; MMP(1,0); BARX;
    MMP(1,1); VM2; BARX;
  }
  asm volatile("s_waitcnt vmcnt(0)" ::: "memory");

  #pragma unroll
  for(int m=0;m<8;m++){
    const int row = row0 + wm*128 + (m>>2)*64 + (m&3)*16 + quad*4;
    #pragma unroll
    for(int n=0;n<4;n++){
      const int col = col0 + wn*64 + n*16 + lid;
      float bv = 0.f;
      if(MODE>=1) bv = bias[col];
      #pragma unroll
      for(int r=0;r<4;r++){
        float v = acc[m][n][r] + bv;
        if(MODE==2) v = v>0.f ? v : expm1f(v);
        Cc[(size_t)(row+r)*ldc + col] = f2bf(v);
      }
    }
  }
#undef STG
#undef DSA
#undef DSB
#undef MMP
#undef BARX
#undef LGKM0
#undef VM2
}

// ---------------- kv^T partials + ksum ----------------
__global__ __launch_bounds__(256) void k_kv(const ushort_t* __restrict__ qkv,
    const ushort_t* __restrict__ projS,
    float* __restrict__ kvp, float* __restrict__ ksum)
{
  __shared__ ushort_t lK[64*64];
  __shared__ ushort_t lvT[2][64*72];
  __shared__ ushort_t lkp[64*72];
  const int chunk=blockIdx.x, mt=blockIdx.y, bh=blockIdx.z;
  const int h=bh&15, b=bh>>4;
  const int tid=threadIdx.x, wave=tid>>6, lane=tid&63, quad=lane>>4, lid=lane&15;

  s8v pf[4][2];
  {
    const ushort_t* projM = projS + mt*64*64;
    #pragma unroll
    for(int n=0;n<4;n++)
      #pragma unroll
      for(int ks=0;ks<2;ks++)
        pf[n][ks] = *(const s8v*)(projM + (n*16+lid)*64 + ks*32 + quad*8);
  }
  f4v kvacc[4];
  #pragma unroll
  for(int j=0;j<4;j++){ f4v z={0.f,0.f,0.f,0.f}; kvacc[j]=z; }
  float ksacc[4] = {};

  const int sl = tid>>3;
  const int gcb = (tid&7) ^ (sl&7);
  const size_t lbase = (size_t)(b*4096 + chunk*1024);
  const ushort_t* gK0 = qkv + (lbase + sl     )*3072 + 1024 + h*64 + gcb*8;
  const ushort_t* gK1 = qkv + (lbase + sl + 32)*3072 + 1024 + h*64 + gcb*8;
  ushort_t* lK0 = &lK[(wave*8     )*64];
  ushort_t* lK1 = &lK[(wave*8 + 32)*64];
  const ushort_t* gV = qkv + (lbase + lane)*3072 + 2048 + h*64 + wave*16;

  for(int it=0; it<16; it++){
    const int p = it&1;
    GLDS16(gK0, lK0);
    GLDS16(gK1, lK1);
    {
      s8v v0 = *(const s8v*)gV;
      s8v v1 = *(const s8v*)(gV + 8);
      #pragma unroll
      for(int jj=0;jj<8;jj++){
        lvT[p][(wave*16+jj  )*72 + lane] = (ushort_t)v0[jj];
        lvT[p][(wave*16+8+jj)*72 + lane] = (ushort_t)v1[jj];
      }
    }
    gK0 += 64*3072; gK1 += 64*3072; gV += 64*3072;
    __syncthreads();
    float dv;
    {
      const int rl = wave*16 + (lane>>2);
      const int cb0 = 2*(lane&3);
      s8v u0 = *(const s8v*)&lK[rl*64 + ((cb0  )^(rl&7))*8];
      s8v u1 = *(const s8v*)&lK[rl*64 + ((cb0+1)^(rl&7))*8];
      float s = 0.f;
      #pragma unroll
      for(int jj=0;jj<8;jj++){
        float f0=bf2f(u0[jj]), f1=bf2f(u1[jj]);
        s += f0*f0 + f1*f1;
      }
      s += __shfl_xor(s,1,64); s += __shfl_xor(s,2,64);
      dv = s*(1.f/16.f);
    }
    f4v dd[4];
    #pragma unroll
    for(int n=0;n<4;n++){ f4v z={0.f,0.f,0.f,0.f}; dd[n]=z; }
    {
      const int ra = wave*16 + lid;
      #pragma unroll
      for(int ks=0;ks<2;ks++){
        s8v af = *(const s8v*)&lK[ra*64 + ((ks*4+quad)^(ra&7))*8];
        #pragma unroll
        for(int n=0;n<4;n++) dd[n] = MFMA(af, pf[n][ks], dd[n]);
      }
    }
    const int lrb = wave*16 + quad*4;
    #pragma unroll
    for(int n=0;n<4;n++){
      s4v pk;
      #pragma unroll
      for(int r=0;r<4;r++){
        float dg = __shfl(dv, (quad*4+r)*4, 64);
        float ekp = __expf(dd[n][r] - dg) + 1e-6f;
        ksacc[n] += ekp;
        pk[r] = (short)f2bf(ekp);
      }
      *(s4v*)&lkp[(n*16+lid)*72 + lrb] = pk;
    }
    __syncthreads();
    #pragma unroll
    for(int ks=0;ks<2;ks++){
      s8v af = *(const s8v*)&lkp[(wave*16+lid)*72 + ks*32 + quad*8];
      #pragma unroll
      for(int j=0;j<4;j++){
        s8v bfr = *(const s8v*)&lvT[p][(j*16+lid)*72 + ks*32 + quad*8];
        kvacc[j] = MFMA(af, bfr, kvacc[j]);
      }
    }
  }
  #pragma unroll
  for(int n=0;n<4;n++){
    float s = ksacc[n];
    s += __shfl_xor(s,16,64); s += __shfl_xor(s,32,64);
    if(quad==0) atomicAdd(&ksum[((size_t)b*16+h)*256 + mt*64 + n*16 + lid], s);
  }
  float* kvo = kvp + ((size_t)chunk*64 + bh)*16384;
  #pragma unroll
  for(int j=0;j<4;j++)
    #pragma unroll
    for(int r=0;r<4;r++)
      kvo[(mt*64 + wave*16 + quad*4 + r)*64 + j*16 + lid] = kvacc[j][r];
}

// ---------------- reduce 4 kv partials + transpose to bf16 [dh][m] ----------------
__global__ __launch_bounds__(256) void k_f2bt(const float* __restrict__ kvp,
    ushort_t* __restrict__ kvb)
{
  __shared__ ushort_t tb[64*68];
  const int mt=blockIdx.x, bh=blockIdx.y;
  const int tid=threadIdx.x;
  {
    const int ml=tid>>2, dg=(tid&3)*16;
    float s[16];
    #pragma unroll
    for(int e=0;e<16;e++) s[e]=0.f;
    #pragma unroll
    for(int c=0;c<4;c++){
      const float* pb = kvp + ((size_t)(c*64+bh)*256 + mt*64+ml)*64 + dg;
      #pragma unroll
      for(int e4=0;e4<4;e4++){
        f4v v = *(const f4v*)(pb + e4*4);
        #pragma unroll
        for(int j=0;j<4;j++) s[e4*4+j] += v[j];
      }
    }
    #pragma unroll
    for(int e=0;e<16;e++) tb[ml*68 + dg + e] = f2bf(s[e]);
  }
  __syncthreads();
  {
    const int dh=tid>>2, mg=(tid&3)*16;
    ushort_t* ob = kvb + (size_t)bh*16384 + (size_t)dh*256 + mt*64 + mg;
    #pragma unroll
    for(int e4=0;e4<4;e4++){
      s4v o;
      #pragma unroll
      for(int j=0;j<4;j++) o[j] = (short)tb[(mg+e4*4+j)*68 + dh];
      *(s4v*)(ob + e4*4) = o;
    }
  }
}

// ---------------- fused attention (per b,h,128 rows) ----------------
__global__ __launch_bounds__(256,3) void k_attn(const ushort_t* __restrict__ qkv,
    const ushort_t* __restrict__ projS, const ushort_t* __restrict__ kvT,
    const float* __restrict__ ksum, ushort_t* __restrict__ attnW)
{
  __shared__ ushort_t lkv[64*256];   // [dh][m], col-blocks XOR-swizzled by dh&7
  __shared__ ushort_t lqp[64*136];   // [l][m-chunk], stride 136
  const int lt=blockIdx.x, h=blockIdx.y, b=blockIdx.z;
  const int tid=threadIdx.x, wave=tid>>6, lane=tid&63, quad=lane>>4, lid=lane&15;
  const ushort_t* kvbG = kvT + ((size_t)b*16+h)*(64*256);
  const float* ksb = ksum + ((size_t)b*16+h)*256;
  float kse[16];
  #pragma unroll
  for(int n=0;n<16;n++) kse[n] = ksb[n*16+lid];
  const int sdh = tid>>5;            // staging: row-in-group 0..7
  const int scb = tid&31;            // staging: 8-elem col-block

  #pragma unroll
  for(int t=0;t<2;t++){
    const int l0 = lt*128 + t*64;
    const ushort_t* qbase = qkv + (size_t)(b*4096+l0+wave*16+lid)*3072 + h*64;
    const s8v af0 = *(const s8v*)(qbase + quad*8);
    const s8v af1 = *(const s8v*)(qbase + 32 + quad*8);
    f4v num[4];
    #pragma unroll
    for(int j=0;j<4;j++){ f4v z={0.f,0.f,0.f,0.f}; num[j]=z; }
    float dnm[4] = {0.f,0.f,0.f,0.f};

    #pragma unroll
    for(int mc=0; mc<2; mc++){
      f4v dd[8];
      #pragma unroll
      for(int n=0;n<8;n++){ f4v z={0.f,0.f,0.f,0.f}; dd[n]=z; }
      #pragma unroll
      for(int n=0;n<8;n++){
        const ushort_t* pb = projS + ((mc*8+n)*16+lid)*64 + quad*8;
        s8v b0 = *(const s8v*)(pb);
        s8v b1 = *(const s8v*)(pb + 32);
        dd[n] = MFMA(af0, b0, dd[n]);
        dd[n] = MFMA(af1, b1, dd[n]);
      }
      if(t==0 && mc==0){
        __builtin_amdgcn_sched_barrier(0);
        #pragma unroll
        for(int q=0;q<8;q++){
          const int dh = q*8 + sdh;
          GLDS16(kvbG + dh*256 + ((scb ^ (dh&7))*8),
                 &lkv[(size_t)(q*8 + wave*2)*256]);
        }
        __builtin_amdgcn_sched_barrier(0);
      }
      #pragma unroll
      for(int r=0;r<4;r++){
        const int lrow = wave*16 + quad*4 + r;
        #pragma unroll
        for(int n=0;n<8;n++){
          float e = __expf(dd[n][r]) + 1e-6f;
          dnm[r] += e * kse[mc*8+n];
          lqp[lrow*136 + n*16 + lid] = f2bf(e);
        }
      }
      if(t==0 && mc==0){
        asm volatile("s_waitcnt vmcnt(0)" ::: "memory");
        __syncthreads();
      } else {
        asm volatile("s_waitcnt lgkmcnt(0)" ::: "memory");
        __builtin_amdgcn_sched_barrier(0);
      }
      #pragma unroll
      for(int ks=0;ks<4;ks++){
        s8v a = *(const s8v*)&lqp[(wave*16+lid)*136 + ks*32 + quad*8];
        #pragma unroll
        for(int j=0;j<4;j++){
          const int cbr = mc*16 + ks*4 + quad;
          s8v bfr = *(const s8v*)&lkv[(size_t)(j*16+lid)*256 + ((cbr ^ (lid&7))*8)];
          num[j] = MFMA(a, bfr, num[j]);
        }
      }
      asm volatile("s_waitcnt lgkmcnt(0)" ::: "memory");
      __builtin_amdgcn_sched_barrier(0);
    }
    #pragma unroll
    for(int r=0;r<4;r++){
      float s = dnm[r];
      s += __shfl_xor(s,1,64); s += __shfl_xor(s,2,64);
      s += __shfl_xor(s,4,64); s += __shfl_xor(s,8,64);
      dnm[r] = s;
    }
    #pragma unroll
    for(int j=0;j<4;j++)
      #pragma unroll
      for(int r=0;r<4;r++){
        const int row = b*4096 + l0 + wave*16 + quad*4 + r;
        attnW[(size_t)row*3072 + h*64 + j*16 + lid] = f2bf(num[j][r] / dnm[r]);
      }
  }
}

// ---------------- LayerNorm ----------------
__device__ __forceinline__ float blockRed(float s, float* buf, int tid){
  #pragma unroll
  for(int o=1;o<64;o<<=1) s += __shfl_xor(s, o, 64);
  __syncthreads();
  if((tid&63)==0) buf[tid>>6] = s;
  __syncthreads();
  return buf[0]+buf[1]+buf[2]+buf[3];
}
template<int FINAL>
__global__ __launch_bounds__(256) void k_ln(const float* __restrict__ xres,
    const ushort_t* __restrict__ aa, int lda_a,
    const ushort_t* __restrict__ bbf, int lda_b,
    const float* __restrict__ g, const float* __restrict__ be,
    ushort_t* __restrict__ obf, int ldo, float* __restrict__ of)
{
  __shared__ float buf[4];
  const int row = blockIdx.x, tid = threadIdx.x;
  float v[4];
  if(FINAL==0){
    f4v xv = *(const f4v*)(xres + (size_t)row*1024 + tid*4);
    s4v av = *(const s4v*)(aa + (size_t)row*lda_a + tid*4);
    #pragma unroll
    for(int i=0;i<4;i++) v[i] = xv[i] + bf2f(av[i]);
  } else {
    s4v av = *(const s4v*)(aa + (size_t)row*lda_a + tid*4);
    s4v bv = *(const s4v*)(bbf + (size_t)row*lda_b + tid*4);
    #pragma unroll
    for(int i=0;i<4;i++) v[i] = bf2f(av[i]) + bf2f(bv[i]);
  }
  float s = v[0]+v[1]+v[2]+v[3];
  s = blockRed(s, buf, tid);
  const float mu = s * (1.f/1024.f);
  float q = 0.f;
  #pragma unroll
  for(int i=0;i<4;i++){ float d=v[i]-mu; q += d*d; }
  q = blockRed(q, buf, tid);
  const float rs = rsqrtf(q*(1.f/1024.f) + 1e-6f);
  const int col = tid*4;
  #pragma unroll
  for(int i=0;i<4;i++){
    float y = (v[i]-mu)*rs*g[col+i] + be[col+i];
    if(FINAL==0) obf[(size_t)row*ldo + col + i] = f2bf(y);
    else         of[(size_t)row*1024 + col + i] = y;
  }
}

// ---------------- launch ----------------
extern "C" void kernel_launch(void* const* d_in, const int* in_sizes, int n_in,
                              void* d_out, int out_size, void* d_ws, size_t ws_size,
                              hipStream_t stream) {
  (void)in_sizes; (void)n_in; (void)out_size;
  const float* x    = (const float*)d_in[0];
  const float* wq   = (const float*)d_in[1];
  const float* wk   = (const float*)d_in[2];
  const float* wv   = (const float*)d_in[3];
  const float* wo   = (const float*)d_in[4];
  const float* proj = (const float*)d_in[5];
  const float* ln1g = (const float*)d_in[6];
  const float* ln1b = (const float*)d_in[7];
  const float* ln2g = (const float*)d_in[8];
  const float* ln2b = (const float*)d_in[9];
  const float* w1   = (const float*)d_in[10];
  const float* b1   = (const float*)d_in[11];
  const float* w2   = (const float*)d_in[12];
  const float* b2   = (const float*)d_in[13];

  char* wsb = (char*)d_ws;
  size_t off = 0;
  auto alloc = [&](size_t bytes)->char*{
    char* p = wsb + off; off = (off + bytes + 255) & ~(size_t)255; return p;
  };
  ushort_t* wqkvT = (ushort_t*)alloc(3072ull*1024*2);
  ushort_t* woT   = (ushort_t*)alloc(1024ull*1024*2);
  ushort_t* w1T   = (ushort_t*)alloc(4096ull*1024*2);
  ushort_t* w2T   = (ushort_t*)alloc(1024ull*4096*2);
  ushort_t* projS = (ushort_t*)alloc(256*64*2);
  ushort_t* qkv   = (ushort_t*)alloc(16384ull*3072*2);
  size_t zoff = off;
  float*    ksumb = (float*)alloc(4ull*16*256*4);
  size_t zlen = off - zoff;
  ushort_t* kvb   = (ushort_t*)alloc(4ull*16*64*256*2);

  // FFN hidden buffer: prefer workspace (full 16384 rows, FFN2 gets a
  // full-GPU 256-block grid); fall back to d_out + 2-chunk if ws too small.
  const size_t hbBytes = 16384ull*4096*2;   // 128 MB
  ushort_t* hbWS = nullptr;
  if(off + hbBytes <= ws_size) hbWS = (ushort_t*)alloc(hbBytes);

  ushort_t* out1 = qkv;
  ushort_t* ao   = qkv + 1024;
  ushort_t* attn = qkv + 2048;
  ushort_t* ffn  = qkv + 2048;
  ushort_t* xb   = (ushort_t*)d_out;
  float*    kvp  = (float*)d_out;

  k_cvt_t<<<dim3(16,16),256,0,stream>>>(wq, wqkvT,                1024, 1024);
  k_cvt_t<<<dim3(16,16),256,0,stream>>>(wk, wqkvT + 1024ull*1024, 1024, 1024);
  k_cvt_t<<<dim3(16,16),256,0,stream>>>(wv, wqkvT + 2048ull*1024, 1024, 1024);
  k_cvt_t<<<dim3(16,16),256,0,stream>>>(wo, woT, 1024, 1024);
  k_cvt_t<<<dim3(64,16),256,0,stream>>>(w1, w1T, 4096, 1024);
  k_cvt_t<<<dim3(16,64),256,0,stream>>>(w2, w2T, 1024, 4096);
  k_proj<<<64,256,0,stream>>>(proj, projS);
  k_f2b4<<<16384,256,0,stream>>>(x, xb, 16384*1024/4);
  {
    int nz = (int)(zlen/4);
    k_zero<<<(nz+255)/256,256,0,stream>>>((float*)(wsb+zoff), nz);
  }

  // QKV projection
  gemm8<0><<<dim3(64,12),512,0,stream>>>(xb, 1024, wqkvT, 1024, qkv, 3072, nullptr, 16384, 3072, 1024);
  k_kv<<<dim3(4,4,64),256,0,stream>>>(qkv, projS, kvp, ksumb);
  k_f2bt<<<dim3(4,64),256,0,stream>>>(kvp, kvb);
  k_attn<<<dim3(32,16,4),256,0,stream>>>(qkv, projS, kvb, ksumb, attn);
  // output projection + LN1
  gemm8<0><<<dim3(64,4),512,0,stream>>>(attn, 3072, woT, 1024, ao, 3072, nullptr, 16384, 1024, 1024);
  k_ln<0><<<16384,256,0,stream>>>(x, ao, 3072, nullptr, 0, ln1g, ln1b, out1, 3072, nullptr);
  // FFN
  if(hbWS){
    // unchunked: FFN2 grid 64x4=256 blocks -> one full-GPU round
    gemm8<2><<<dim3(64,16),512,0,stream>>>(out1, 3072, w1T, 1024, hbWS, 4096, b1, 16384, 4096, 1024);
    gemm8<1><<<dim3(64,4),512,0,stream>>>(hbWS, 4096, w2T, 4096, ffn, 3072, b2, 16384, 1024, 4096);
  } else {
    ushort_t* hb = (ushort_t*)d_out;   // kvp dead by now
    for(int c=0;c<2;c++){
      const size_t ro = (size_t)c*8192*3072;
      gemm8<2><<<dim3(32,16),512,0,stream>>>(out1 + ro, 3072, w1T, 1024, hb, 4096, b1, 8192, 4096, 1024);
      gemm8<1><<<dim3(32,4),512,0,stream>>>(hb, 4096, w2T, 4096, ffn + ro, 3072, b2, 8192, 1024, 4096);
    }
  }
  // LN2 -> fp32 out (overwrites all of d_out)
  k_ln<1><<<16384,256,0,stream>>>(nullptr, out1, 3072, ffn, 3072, ln2g, ln2b, nullptr, 0, (float*)d_out);
}

// Round 6
// 743.725 us; speedup vs baseline: 1.4500x; 1.0551x over previous
//
#include <hip/hip_runtime.h>

typedef unsigned short ushort_t;
typedef unsigned int uint_t;
typedef __attribute__((ext_vector_type(8))) short s8v;
typedef __attribute__((ext_vector_type(4))) short s4v;
typedef __attribute__((ext_vector_type(4))) float f4v;

#define MFMA(a,b,c) __builtin_amdgcn_mfma_f32_16x16x32_bf16(a,b,c,0,0,0)

#define GLDS16(g, l) \
  __builtin_amdgcn_global_load_lds((const __attribute__((address_space(1))) void*)(g), \
                                   (__attribute__((address_space(3))) void*)(l), 16, 0, 0)

__device__ __forceinline__ float bf2f(short s){
  return __uint_as_float(((uint_t)(ushort_t)s) << 16);
}
__device__ __forceinline__ ushort_t f2bf(float f){
  uint_t u = __float_as_uint(f);
  u += 0x7fffu + ((u >> 16) & 1u);
  return (ushort_t)(u >> 16);
}

// ---------------- conversions ----------------
__global__ __launch_bounds__(256) void k_cvt_t(const float* __restrict__ src,
    ushort_t* __restrict__ dst, int R, int C){
  __shared__ ushort_t t[64*68];
  const int r0 = blockIdx.x*64, c0 = blockIdx.y*64;
  const int tid = threadIdx.x;
  const int cl = tid>>4, rl4 = (tid&15)*4;
  #pragma unroll
  for(int cc=0; cc<64; cc+=16){
    f4v v = *(const f4v*)(src + (size_t)(c0+cl+cc)*R + r0 + rl4);
    #pragma unroll
    for(int j=0;j<4;j++) t[(rl4+j)*68 + cl+cc] = f2bf(v[j]);
  }
  __syncthreads();
  const int rw = tid>>4, cw4 = (tid&15)*4;
  #pragma unroll
  for(int rr=0; rr<64; rr+=16){
    s4v o;
    #pragma unroll
    for(int j=0;j<4;j++) o[j] = (short)t[(rw+rr)*68 + cw4 + j];
    *(s4v*)(dst + (size_t)(r0+rw+rr)*C + c0 + cw4) = o;
  }
}
__global__ __launch_bounds__(256) void k_proj(const float* __restrict__ src,
    ushort_t* __restrict__ dst){
  int i = blockIdx.x*256 + threadIdx.x;
  if(i < 256*64) dst[i] = f2bf(src[i] * 0.3535533905932738f);
}
__global__ __launch_bounds__(256) void k_f2b4(const float* __restrict__ s,
    ushort_t* __restrict__ d, int n4){
  int i = blockIdx.x*256 + threadIdx.x;
  if(i < n4){
    f4v v = ((const f4v*)s)[i];
    s4v o;
    #pragma unroll
    for(int j=0;j<4;j++) o[j] = (short)f2bf(v[j]);
    ((s4v*)d)[i] = o;
  }
}
__global__ __launch_bounds__(256) void k_zero(float* __restrict__ p, int n){
  int i = blockIdx.x*256 + threadIdx.x;
  if(i < n) p[i] = 0.f;
}

// ============ 256x256 8-phase bf16 GEMM: C[M][N] = A[M][K] * Bt[N][K]^T ============
// G: col-group width for the intra-XCD grouped swizzle (requires gridDim.y % G == 0).
// Each XCD's ~32 concurrent blocks then cover ~8 rows x G cols -> A+B window fits L2.
template<int MODE>
__global__ __launch_bounds__(512,2) void gemm8(const ushort_t* __restrict__ A, int lda,
    const ushort_t* __restrict__ Bt, int ldb, ushort_t* __restrict__ Cc, int ldc,
    const float* __restrict__ bias, int M, int N, int K, int G)
{
  __shared__ ushort_t lsh[4][256*64];   // [buf*2+isB][row*64 + k]
  const int tid = threadIdx.x;
  const int wave = tid>>6, lane = tid&63, quad = lane>>4, lid = lane&15;
  const int wm = wave>>2, wn = wave&3;
  const int nwgx = gridDim.x;
  const int nwg  = nwgx * gridDim.y;
  const int orig = blockIdx.y*nwgx + blockIdx.x;
  const int swz  = (orig&7)*(nwg>>3) + (orig>>3);   // XCD-contiguous chunks
  const int gsz  = nwgx * G;
  const int g    = swz / gsz;
  const int rem  = swz - g*gsz;
  const int r    = rem / G;
  const int c    = g*G + (rem - r*G);
  const int row0 = r*256, col0 = c*256;

  const int srow = lane>>3;
  const int scol = ((lane&7) ^ srow)*8;
  const ushort_t* gA = A  + (size_t)(row0 + wave*8 + srow)*lda + scol;
  const ushort_t* gB = Bt + (size_t)(col0 + wave*8 + srow)*ldb + scol;
  const int ldsw = wave*512;

  const int aoff = (wm*128 + lid)*64;
  const int boff = (wn*64  + lid)*64;
  const int k0s  = (quad*8)        ^ ((lid&7)<<3);
  const int k1s  = (32 + quad*8)   ^ ((lid&7)<<3);

  f4v acc[8][4];
  #pragma unroll
  for(int m=0;m<8;m++)
    #pragma unroll
    for(int n=0;n<4;n++){ f4v z={0.f,0.f,0.f,0.f}; acc[m][n]=z; }
  s8v af[4][2], bf[4][2];

  const int KT = K>>6;
  const int NP = KT>>1;

#define STG(buf, isB, half, kt) do{ \
    const ushort_t* _g = ((isB)? gB : gA) + (size_t)((half)*128)*((isB)? ldb : lda) + (size_t)(kt)*64; \
    GLDS16(_g, &lsh[(buf)*2+(isB)][(half)*8192 + ldsw]); \
    GLDS16(_g + (size_t)64*((isB)? ldb : lda), &lsh[(buf)*2+(isB)][(half)*8192 + 4096 + ldsw]); \
  }while(0)

#define DSA(buf, mh) do{ \
    const ushort_t* _l = &lsh[(buf)*2][aoff + (mh)*4096]; \
    _Pragma("unroll") \
    for(int _m=0;_m<4;_m++){ \
      af[_m][0] = *(const s8v*)(_l + _m*1024 + k0s); \
      af[_m][1] = *(const s8v*)(_l + _m*1024 + k1s); \
    } \
  }while(0)

#define DSB(buf, nh) do{ \
    const ushort_t* _l = &lsh[(buf)*2+1][boff]; \
    _Pragma("unroll") \
    for(int _n=0;_n<2;_n++){ \
      bf[(nh)*2+_n][0] = *(const s8v*)(_l + ((nh)*2+_n)*1024 + k0s); \
      bf[(nh)*2+_n][1] = *(const s8v*)(_l + ((nh)*2+_n)*1024 + k1s); \
    } \
  }while(0)

#define MMP(mh, nh) do{ \
    __builtin_amdgcn_s_setprio(1); \
    _Pragma("unroll") \
    for(int _m=0;_m<4;_m++) \
      _Pragma("unroll") \
      for(int _n=0;_n<2;_n++){ \
        acc[(mh)*4+_m][(nh)*2+_n] = MFMA(af[_m][0], bf[(nh)*2+_n][0], acc[(mh)*4+_m][(nh)*2+_n]); \
        acc[(mh)*4+_m][(nh)*2+_n] = MFMA(af[_m][1], bf[(nh)*2+_n][1], acc[(mh)*4+_m][(nh)*2+_n]); \
      } \
    __builtin_amdgcn_s_setprio(0); \
  }while(0)

#define BARX  __builtin_amdgcn_s_barrier()
#define LGKM0 do{ asm volatile("s_waitcnt lgkmcnt(0)" ::: "memory"); __builtin_amdgcn_sched_barrier(0); }while(0)
#define VM2   do{ asm volatile("s_waitcnt vmcnt(2)"   ::: "memory"); __builtin_amdgcn_sched_barrier(0); }while(0)

  STG(0,0,0,0); STG(0,0,1,0); STG(0,1,0,0); STG(0,1,1,0);
  STG(1,0,0,1);
  VM2;
  BARX;

  for(int p=0; p<NP; p++){
    const int t1 = 2*p+1;
    const int t2 = (2*p+2 < KT)? 2*p+2 : KT-1;
    const int t3 = (2*p+3 < KT)? 2*p+3 : KT-1;
    DSA(0,0); DSB(0,0); STG(1,0,1,t1);
    asm volatile("s_waitcnt lgkmcnt(8)" ::: "memory");
    BARX; LGKM0; MMP(0,0); BARX;
    DSB(0,1); STG(1,1,0,t1); STG(1,1,1,t1);
    BARX; LGKM0; MMP(0,1); BARX;
    DSA(0,1); STG(0,0,0,t2);
    BARX; LGKM0; MMP(1,0); BARX;
    MMP(1,1); VM2; BARX;
    DSA(1,0); DSB(1,0); STG(0,0,1,t2);
    asm volatile("s_waitcnt lgkmcnt(8)" ::: "memory");
    BARX; LGKM0; MMP(0,0); BARX;
    DSB(1,1); STG(0,1,0,t2); STG(0,1,1,t2);
    BARX; LGKM0; MMP(0,1); BARX;
    DSA(1,1); STG(1,0,0,t3);
    BARX; LGKM0; MMP(1,0); BARX;
    MMP(1,1); VM2; BARX;
  }
  asm volatile("s_waitcnt vmcnt(0)" ::: "memory");

  #pragma unroll
  for(int m=0;m<8;m++){
    const int row = row0 + wm*128 + (m>>2)*64 + (m&3)*16 + quad*4;
    #pragma unroll
    for(int n=0;n<4;n++){
      const int col = col0 + wn*64 + n*16 + lid;
      float bv = 0.f;
      if(MODE>=1) bv = bias[col];
      #pragma unroll
      for(int rr=0;rr<4;rr++){
        float v = acc[m][n][rr] + bv;
        if(MODE==2) v = v>0.f ? v : (__expf(v) - 1.0f);   // fast ELU (bf16-accurate)
        Cc[(size_t)(row+rr)*ldc + col] = f2bf(v);
      }
    }
  }
#undef STG
#undef DSA
#undef DSB
#undef MMP
#undef BARX
#undef LGKM0
#undef VM2
}

// ---------------- kv^T partials + ksum ----------------
__global__ __launch_bounds__(256) void k_kv(const ushort_t* __restrict__ qkv,
    const ushort_t* __restrict__ projS,
    float* __restrict__ kvp, float* __restrict__ ksum)
{
  __shared__ ushort_t lK[64*64];
  __shared__ ushort_t lvT[2][64*72];
  __shared__ ushort_t lkp[64*72];
  const int chunk=blockIdx.x, mt=blockIdx.y, bh=blockIdx.z;
  const int h=bh&15, b=bh>>4;
  const int tid=threadIdx.x, wave=tid>>6, lane=tid&63, quad=lane>>4, lid=lane&15;

  s8v pf[4][2];
  {
    const ushort_t* projM = projS + mt*64*64;
    #pragma unroll
    for(int n=0;n<4;n++)
      #pragma unroll
      for(int ks=0;ks<2;ks++)
        pf[n][ks] = *(const s8v*)(projM + (n*16+lid)*64 + ks*32 + quad*8);
  }
  f4v kvacc[4];
  #pragma unroll
  for(int j=0;j<4;j++){ f4v z={0.f,0.f,0.f,0.f}; kvacc[j]=z; }
  float ksacc[4] = {};

  const int sl = tid>>3;
  const int gcb = (tid&7) ^ (sl&7);
  const size_t lbase = (size_t)(b*4096 + chunk*1024);
  const ushort_t* gK0 = qkv + (lbase + sl     )*3072 + 1024 + h*64 + gcb*8;
  const ushort_t* gK1 = qkv + (lbase + sl + 32)*3072 + 1024 + h*64 + gcb*8;
  ushort_t* lK0 = &lK[(wave*8     )*64];
  ushort_t* lK1 = &lK[(wave*8 + 32)*64];
  const ushort_t* gV = qkv + (lbase + lane)*3072 + 2048 + h*64 + wave*16;

  for(int it=0; it<16; it++){
    const int p = it&1;
    GLDS16(gK0, lK0);
    GLDS16(gK1, lK1);
    {
      s8v v0 = *(const s8v*)gV;
      s8v v1 = *(const s8v*)(gV + 8);
      #pragma unroll
      for(int jj=0;jj<8;jj++){
        lvT[p][(wave*16+jj  )*72 + lane] = (ushort_t)v0[jj];
        lvT[p][(wave*16+8+jj)*72 + lane] = (ushort_t)v1[jj];
      }
    }
    gK0 += 64*3072; gK1 += 64*3072; gV += 64*3072;
    __syncthreads();
    float dv;
    {
      const int rl = wave*16 + (lane>>2);
      const int cb0 = 2*(lane&3);
      s8v u0 = *(const s8v*)&lK[rl*64 + ((cb0  )^(rl&7))*8];
      s8v u1 = *(const s8v*)&lK[rl*64 + ((cb0+1)^(rl&7))*8];
      float s = 0.f;
      #pragma unroll
      for(int jj=0;jj<8;jj++){
        float f0=bf2f(u0[jj]), f1=bf2f(u1[jj]);
        s += f0*f0 + f1*f1;
      }
      s += __shfl_xor(s,1,64); s += __shfl_xor(s,2,64);
      dv = s*(1.f/16.f);
    }
    f4v dd[4];
    #pragma unroll
    for(int n=0;n<4;n++){ f4v z={0.f,0.f,0.f,0.f}; dd[n]=z; }
    {
      const int ra = wave*16 + lid;
      #pragma unroll
      for(int ks=0;ks<2;ks++){
        s8v af = *(const s8v*)&lK[ra*64 + ((ks*4+quad)^(ra&7))*8];
        #pragma unroll
        for(int n=0;n<4;n++) dd[n] = MFMA(af, pf[n][ks], dd[n]);
      }
    }
    const int lrb = wave*16 + quad*4;
    #pragma unroll
    for(int n=0;n<4;n++){
      s4v pk;
      #pragma unroll
      for(int r=0;r<4;r++){
        float dg = __shfl(dv, (quad*4+r)*4, 64);
        float ekp = __expf(dd[n][r] - dg) + 1e-6f;
        ksacc[n] += ekp;
        pk[r] = (short)f2bf(ekp);
      }
      *(s4v*)&lkp[(n*16+lid)*72 + lrb] = pk;
    }
    __syncthreads();
    #pragma unroll
    for(int ks=0;ks<2;ks++){
      s8v af = *(const s8v*)&lkp[(wave*16+lid)*72 + ks*32 + quad*8];
      #pragma unroll
      for(int j=0;j<4;j++){
        s8v bfr = *(const s8v*)&lvT[p][(j*16+lid)*72 + ks*32 + quad*8];
        kvacc[j] = MFMA(af, bfr, kvacc[j]);
      }
    }
  }
  #pragma unroll
  for(int n=0;n<4;n++){
    float s = ksacc[n];
    s += __shfl_xor(s,16,64); s += __shfl_xor(s,32,64);
    if(quad==0) atomicAdd(&ksum[((size_t)b*16+h)*256 + mt*64 + n*16 + lid], s);
  }
  float* kvo = kvp + ((size_t)chunk*64 + bh)*16384;
  #pragma unroll
  for(int j=0;j<4;j++)
    #pragma unroll
    for(int r=0;r<4;r++)
      kvo[(mt*64 + wave*16 + quad*4 + r)*64 + j*16 + lid] = kvacc[j][r];
}

// ---------------- reduce 4 kv partials + transpose to bf16 [dh][m] ----------------
__global__ __launch_bounds__(256) void k_f2bt(const float* __restrict__ kvp,
    ushort_t* __restrict__ kvb)
{
  __shared__ ushort_t tb[64*68];
  const int mt=blockIdx.x, bh=blockIdx.y;
  const int tid=threadIdx.x;
  {
    const int ml=tid>>2, dg=(tid&3)*16;
    float s[16];
    #pragma unroll
    for(int e=0;e<16;e++) s[e]=0.f;
    #pragma unroll
    for(int c=0;c<4;c++){
      const float* pb = kvp + ((size_t)(c*64+bh)*256 + mt*64+ml)*64 + dg;
      #pragma unroll
      for(int e4=0;e4<4;e4++){
        f4v v = *(const f4v*)(pb + e4*4);
        #pragma unroll
        for(int j=0;j<4;j++) s[e4*4+j] += v[j];
      }
    }
    #pragma unroll
    for(int e=0;e<16;e++) tb[ml*68 + dg + e] = f2bf(s[e]);
  }
  __syncthreads();
  {
    const int dh=tid>>2, mg=(tid&3)*16;
    ushort_t* ob = kvb + (size_t)bh*16384 + (size_t)dh*256 + mt*64 + mg;
    #pragma unroll
    for(int e4=0;e4<4;e4++){
      s4v o;
      #pragma unroll
      for(int j=0;j<4;j++) o[j] = (short)tb[(mg+e4*4+j)*68 + dh];
      *(s4v*)(ob + e4*4) = o;
    }
  }
}

// ---------------- fused attention (per b,h,128 rows) ----------------
__global__ __launch_bounds__(256,3) void k_attn(const ushort_t* __restrict__ qkv,
    const ushort_t* __restrict__ projS, const ushort_t* __restrict__ kvT,
    const float* __restrict__ ksum, ushort_t* __restrict__ attnW)
{
  __shared__ ushort_t lkv[64*256];   // [dh][m], col-blocks XOR-swizzled by dh&7
  __shared__ ushort_t lqp[64*136];   // [l][m-chunk], stride 136
  const int lt=blockIdx.x, h=blockIdx.y, b=blockIdx.z;
  const int tid=threadIdx.x, wave=tid>>6, lane=tid&63, quad=lane>>4, lid=lane&15;
  const ushort_t* kvbG = kvT + ((size_t)b*16+h)*(64*256);
  const float* ksb = ksum + ((size_t)b*16+h)*256;
  float kse[16];
  #pragma unroll
  for(int n=0;n<16;n++) kse[n] = ksb[n*16+lid];
  const int sdh = tid>>5;            // staging: row-in-group 0..7
  const int scb = tid&31;            // staging: 8-elem col-block

  #pragma unroll
  for(int t=0;t<2;t++){
    const int l0 = lt*128 + t*64;
    const ushort_t* qbase = qkv + (size_t)(b*4096+l0+wave*16+lid)*3072 + h*64;
    const s8v af0 = *(const s8v*)(qbase + quad*8);
    const s8v af1 = *(const s8v*)(qbase + 32 + quad*8);
    f4v num[4];
    #pragma unroll
    for(int j=0;j<4;j++){ f4v z={0.f,0.f,0.f,0.f}; num[j]=z; }
    float dnm[4] = {0.f,0.f,0.f,0.f};

    #pragma unroll
    for(int mc=0; mc<2; mc++){
      f4v dd[8];
      #pragma unroll
      for(int n=0;n<8;n++){ f4v z={0.f,0.f,0.f,0.f}; dd[n]=z; }
      #pragma unroll
      for(int n=0;n<8;n++){
        const ushort_t* pb = projS + ((mc*8+n)*16+lid)*64 + quad*8;
        s8v b0 = *(const s8v*)(pb);
        s8v b1 = *(const s8v*)(pb + 32);
        dd[n] = MFMA(af0, b0, dd[n]);
        dd[n] = MFMA(af1, b1, dd[n]);
      }
      if(t==0 && mc==0){
        __builtin_amdgcn_sched_barrier(0);
        #pragma unroll
        for(int q=0;q<8;q++){
          const int dh = q*8 + sdh;
          GLDS16(kvbG + dh*256 + ((scb ^ (dh&7))*8),
                 &lkv[(size_t)(q*8 + wave*2)*256]);
        }
        __builtin_amdgcn_sched_barrier(0);
      }
      #pragma unroll
      for(int r=0;r<4;r++){
        const int lrow = wave*16 + quad*4 + r;
        #pragma unroll
        for(int n=0;n<8;n++){
          float e = __expf(dd[n][r]) + 1e-6f;
          dnm[r] += e * kse[mc*8+n];
          lqp[lrow*136 + n*16 + lid] = f2bf(e);
        }
      }
      if(t==0 && mc==0){
        asm volatile("s_waitcnt vmcnt(0)" ::: "memory");
        __syncthreads();
      } else {
        asm volatile("s_waitcnt lgkmcnt(0)" ::: "memory");
        __builtin_amdgcn_sched_barrier(0);
      }
      #pragma unroll
      for(int ks=0;ks<4;ks++){
        s8v a = *(const s8v*)&lqp[(wave*16+lid)*136 + ks*32 + quad*8];
        #pragma unroll
        for(int j=0;j<4;j++){
          const int cbr = mc*16 + ks*4 + quad;
          s8v bfr = *(const s8v*)&lkv[(size_t)(j*16+lid)*256 + ((cbr ^ (lid&7))*8)];
          num[j] = MFMA(a, bfr, num[j]);
        }
      }
      asm volatile("s_waitcnt lgkmcnt(0)" ::: "memory");
      __builtin_amdgcn_sched_barrier(0);
    }
    #pragma unroll
    for(int r=0;r<4;r++){
      float s = dnm[r];
      s += __shfl_xor(s,1,64); s += __shfl_xor(s,2,64);
      s += __shfl_xor(s,4,64); s += __shfl_xor(s,8,64);
      dnm[r] = s;
    }
    #pragma unroll
    for(int j=0;j<4;j++)
      #pragma unroll
      for(int r=0;r<4;r++){
        const int row = b*4096 + l0 + wave*16 + quad*4 + r;
        attnW[(size_t)row*3072 + h*64 + j*16 + lid] = f2bf(num[j][r] / dnm[r]);
      }
  }
}

// ---------------- LayerNorm ----------------
__device__ __forceinline__ float blockRed(float s, float* buf, int tid){
  #pragma unroll
  for(int o=1;o<64;o<<=1) s += __shfl_xor(s, o, 64);
  __syncthreads();
  if((tid&63)==0) buf[tid>>6] = s;
  __syncthreads();
  return buf[0]+buf[1]+buf[2]+buf[3];
}
template<int FINAL>
__global__ __launch_bounds__(256) void k_ln(const float* __restrict__ xres,
    const ushort_t* __restrict__ aa, int lda_a,
    const ushort_t* __restrict__ bbf, int lda_b,
    const float* __restrict__ g, const float* __restrict__ be,
    ushort_t* __restrict__ obf, int ldo, float* __restrict__ of)
{
  __shared__ float buf[4];
  const int row = blockIdx.x, tid = threadIdx.x;
  float v[4];
  if(FINAL==0){
    f4v xv = *(const f4v*)(xres + (size_t)row*1024 + tid*4);
    s4v av = *(const s4v*)(aa + (size_t)row*lda_a + tid*4);
    #pragma unroll
    for(int i=0;i<4;i++) v[i] = xv[i] + bf2f(av[i]);
  } else {
    s4v av = *(const s4v*)(aa + (size_t)row*lda_a + tid*4);
    s4v bv = *(const s4v*)(bbf + (size_t)row*lda_b + tid*4);
    #pragma unroll
    for(int i=0;i<4;i++) v[i] = bf2f(av[i]) + bf2f(bv[i]);
  }
  float s = v[0]+v[1]+v[2]+v[3];
  s = blockRed(s, buf, tid);
  const float mu = s * (1.f/1024.f);
  float q = 0.f;
  #pragma unroll
  for(int i=0;i<4;i++){ float d=v[i]-mu; q += d*d; }
  q = blockRed(q, buf, tid);
  const float rs = rsqrtf(q*(1.f/1024.f) + 1e-6f);
  const int col = tid*4;
  #pragma unroll
  for(int i=0;i<4;i++){
    float y = (v[i]-mu)*rs*g[col+i] + be[col+i];
    if(FINAL==0) obf[(size_t)row*ldo + col + i] = f2bf(y);
    else         of[(size_t)row*1024 + col + i] = y;
  }
}

// ---------------- launch ----------------
extern "C" void kernel_launch(void* const* d_in, const int* in_sizes, int n_in,
                              void* d_out, int out_size, void* d_ws, size_t ws_size,
                              hipStream_t stream) {
  (void)in_sizes; (void)n_in; (void)out_size;
  const float* x    = (const float*)d_in[0];
  const float* wq   = (const float*)d_in[1];
  const float* wk   = (const float*)d_in[2];
  const float* wv   = (const float*)d_in[3];
  const float* wo   = (const float*)d_in[4];
  const float* proj = (const float*)d_in[5];
  const float* ln1g = (const float*)d_in[6];
  const float* ln1b = (const float*)d_in[7];
  const float* ln2g = (const float*)d_in[8];
  const float* ln2b = (const float*)d_in[9];
  const float* w1   = (const float*)d_in[10];
  const float* b1   = (const float*)d_in[11];
  const float* w2   = (const float*)d_in[12];
  const float* b2   = (const float*)d_in[13];

  char* wsb = (char*)d_ws;
  size_t off = 0;
  auto alloc = [&](size_t bytes)->char*{
    char* p = wsb + off; off = (off + bytes + 255) & ~(size_t)255; return p;
  };
  ushort_t* wqkvT = (ushort_t*)alloc(3072ull*1024*2);
  ushort_t* woT   = (ushort_t*)alloc(1024ull*1024*2);
  ushort_t* w1T   = (ushort_t*)alloc(4096ull*1024*2);
  ushort_t* w2T   = (ushort_t*)alloc(1024ull*4096*2);
  ushort_t* projS = (ushort_t*)alloc(256*64*2);
  ushort_t* qkv   = (ushort_t*)alloc(16384ull*3072*2);
  size_t zoff = off;
  float*    ksumb = (float*)alloc(4ull*16*256*4);
  size_t zlen = off - zoff;
  ushort_t* kvb   = (ushort_t*)alloc(4ull*16*64*256*2);

  // FFN hidden buffer: prefer workspace (full 16384 rows, FFN2 gets a
  // full-GPU 256-block grid); fall back to d_out + 2-chunk if ws too small.
  const size_t hbBytes = 16384ull*4096*2;   // 128 MB
  ushort_t* hbWS = nullptr;
  if(off + hbBytes <= ws_size) hbWS = (ushort_t*)alloc(hbBytes);

  ushort_t* out1 = qkv;
  ushort_t* ao   = qkv + 1024;
  ushort_t* attn = qkv + 2048;
  ushort_t* ffn  = qkv + 2048;
  ushort_t* xb   = (ushort_t*)d_out;
  float*    kvp  = (float*)d_out;

  k_cvt_t<<<dim3(16,16),256,0,stream>>>(wq, wqkvT,                1024, 1024);
  k_cvt_t<<<dim3(16,16),256,0,stream>>>(wk, wqkvT + 1024ull*1024, 1024, 1024);
  k_cvt_t<<<dim3(16,16),256,0,stream>>>(wv, wqkvT + 2048ull*1024, 1024, 1024);
  k_cvt_t<<<dim3(16,16),256,0,stream>>>(wo, woT, 1024, 1024);
  k_cvt_t<<<dim3(64,16),256,0,stream>>>(w1, w1T, 4096, 1024);
  k_cvt_t<<<dim3(16,64),256,0,stream>>>(w2, w2T, 1024, 4096);
  k_proj<<<64,256,0,stream>>>(proj, projS);
  k_f2b4<<<16384,256,0,stream>>>(x, xb, 16384*1024/4);
  {
    int nz = (int)(zlen/4);
    k_zero<<<(nz+255)/256,256,0,stream>>>((float*)(wsb+zoff), nz);
  }

  // QKV projection
  gemm8<0><<<dim3(64,12),512,0,stream>>>(xb, 1024, wqkvT, 1024, qkv, 3072, nullptr, 16384, 3072, 1024, 4);
  k_kv<<<dim3(4,4,64),256,0,stream>>>(qkv, projS, kvp, ksumb);
  k_f2bt<<<dim3(4,64),256,0,stream>>>(kvp, kvb);
  k_attn<<<dim3(32,16,4),256,0,stream>>>(qkv, projS, kvb, ksumb, attn);
  // output projection + LN1
  gemm8<0><<<dim3(64,4),512,0,stream>>>(attn, 3072, woT, 1024, ao, 3072, nullptr, 16384, 1024, 1024, 4);
  k_ln<0><<<16384,256,0,stream>>>(x, ao, 3072, nullptr, 0, ln1g, ln1b, out1, 3072, nullptr);
  // FFN
  if(hbWS){
    gemm8<2><<<dim3(64,16),512,0,stream>>>(out1, 3072, w1T, 1024, hbWS, 4096, b1, 16384, 4096, 1024, 8);
    gemm8<1><<<dim3(64,4),512,0,stream>>>(hbWS, 4096, w2T, 4096, ffn, 3072, b2, 16384, 1024, 4096, 4);
  } else {
    ushort_t* hb = (ushort_t*)d_out;   // kvp dead by now
    for(int c=0;c<2;c++){
      const size_t ro = (size_t)c*8192*3072;
      gemm8<2><<<dim3(32,16),512,0,stream>>>(out1 + ro, 3072, w1T, 1024, hb, 4096, b1, 8192, 4096, 1024, 8);
      gemm8<1><<<dim3(32,4),512,0,stream>>>(hb, 4096, w2T, 4096, ffn + ro, 3072, b2, 8192, 1024, 4096, 4);
    }
  }
  // LN2 -> fp32 out (overwrites all of d_out)
  k_ln<1><<<16384,256,0,stream>>>(nullptr, out1, 3072, ffn, 3072, ln2g, ln2b, nullptr, 0, (float*)d_out);
}

// Round 9
// 733.818 us; speedup vs baseline: 1.4695x; 1.0135x over previous
//
#include <hip/hip_runtime.h>

typedef unsigned short ushort_t;
typedef unsigned int uint_t;
typedef __attribute__((ext_vector_type(8))) short s8v;
typedef __attribute__((ext_vector_type(4))) short s4v;
typedef __attribute__((ext_vector_type(4))) float f4v;

#define MFMA(a,b,c) __builtin_amdgcn_mfma_f32_16x16x32_bf16(a,b,c,0,0,0)

#define GLDS16(g, l) \
  __builtin_amdgcn_global_load_lds((const __attribute__((address_space(1))) void*)(g), \
                                   (__attribute__((address_space(3))) void*)(l), 16, 0, 0)

__device__ __forceinline__ float bf2f(short s){
  return __uint_as_float(((uint_t)(ushort_t)s) << 16);
}
__device__ __forceinline__ ushort_t f2bf(float f){
  uint_t u = __float_as_uint(f);
  u += 0x7fffu + ((u >> 16) & 1u);
  return (ushort_t)(u >> 16);
}

// ---------------- conversions ----------------
__global__ __launch_bounds__(256) void k_cvt_t(const float* __restrict__ src,
    ushort_t* __restrict__ dst, int R, int C){
  __shared__ ushort_t t[64*68];
  const int r0 = blockIdx.x*64, c0 = blockIdx.y*64;
  const int tid = threadIdx.x;
  const int cl = tid>>4, rl4 = (tid&15)*4;
  #pragma unroll
  for(int cc=0; cc<64; cc+=16){
    f4v v = *(const f4v*)(src + (size_t)(c0+cl+cc)*R + r0 + rl4);
    #pragma unroll
    for(int j=0;j<4;j++) t[(rl4+j)*68 + cl+cc] = f2bf(v[j]);
  }
  __syncthreads();
  const int rw = tid>>4, cw4 = (tid&15)*4;
  #pragma unroll
  for(int rr=0; rr<64; rr+=16){
    s4v o;
    #pragma unroll
    for(int j=0;j<4;j++) o[j] = (short)t[(rw+rr)*68 + cw4 + j];
    *(s4v*)(dst + (size_t)(r0+rw+rr)*C + c0 + cw4) = o;
  }
}
__global__ __launch_bounds__(256) void k_proj(const float* __restrict__ src,
    ushort_t* __restrict__ dst){
  int i = blockIdx.x*256 + threadIdx.x;
  if(i < 256*64) dst[i] = f2bf(src[i] * 0.3535533905932738f);
}
__global__ __launch_bounds__(256) void k_f2b4(const float* __restrict__ s,
    ushort_t* __restrict__ d, int n4){
  int i = blockIdx.x*256 + threadIdx.x;
  if(i < n4){
    f4v v = ((const f4v*)s)[i];
    s4v o;
    #pragma unroll
    for(int j=0;j<4;j++) o[j] = (short)f2bf(v[j]);
    ((s4v*)d)[i] = o;
  }
}
__global__ __launch_bounds__(256) void k_zero(float* __restrict__ p, int n){
  int i = blockIdx.x*256 + threadIdx.x;
  if(i < n) p[i] = 0.f;
}

// ============ 256x256 8-phase bf16 GEMM: C[M][N] = A[M][K] * Bt[N][K]^T ============
// G: col-group width for the intra-XCD grouped swizzle (requires gridDim.y % G == 0).
template<int MODE>
__global__ __launch_bounds__(512,2) void gemm8(const ushort_t* __restrict__ A, int lda,
    const ushort_t* __restrict__ Bt, int ldb, ushort_t* __restrict__ Cc, int ldc,
    const float* __restrict__ bias, int M, int N, int K, int G)
{
  __shared__ ushort_t lsh[4][256*64];   // [buf*2+isB][row*64 + k]
  const int tid = threadIdx.x;
  const int wave = tid>>6, lane = tid&63, quad = lane>>4, lid = lane&15;
  const int wm = wave>>2, wn = wave&3;
  const int nwgx = gridDim.x;
  const int nwg  = nwgx * gridDim.y;
  const int orig = blockIdx.y*nwgx + blockIdx.x;
  const int swz  = (orig&7)*(nwg>>3) + (orig>>3);   // XCD-contiguous chunks
  const int gsz  = nwgx * G;
  const int g    = swz / gsz;
  const int rem  = swz - g*gsz;
  const int r    = rem / G;
  const int c    = g*G + (rem - r*G);
  const int row0 = r*256, col0 = c*256;

  const int srow = lane>>3;
  const int scol = ((lane&7) ^ srow)*8;
  const ushort_t* gA = A  + (size_t)(row0 + wave*8 + srow)*lda + scol;
  const ushort_t* gB = Bt + (size_t)(col0 + wave*8 + srow)*ldb + scol;
  const int ldsw = wave*512;

  const int aoff = (wm*128 + lid)*64;
  const int boff = (wn*64  + lid)*64;
  const int k0s  = (quad*8)        ^ ((lid&7)<<3);
  const int k1s  = (32 + quad*8)   ^ ((lid&7)<<3);

  f4v acc[8][4];
  #pragma unroll
  for(int m=0;m<8;m++)
    #pragma unroll
    for(int n=0;n<4;n++){ f4v z={0.f,0.f,0.f,0.f}; acc[m][n]=z; }
  s8v af[4][2], bf[4][2];

  const int KT = K>>6;
  const int NP = KT>>1;

#define STG(buf, isB, half, kt) do{ \
    const ushort_t* _g = ((isB)? gB : gA) + (size_t)((half)*128)*((isB)? ldb : lda) + (size_t)(kt)*64; \
    GLDS16(_g, &lsh[(buf)*2+(isB)][(half)*8192 + ldsw]); \
    GLDS16(_g + (size_t)64*((isB)? ldb : lda), &lsh[(buf)*2+(isB)][(half)*8192 + 4096 + ldsw]); \
  }while(0)

#define DSA(buf, mh) do{ \
    const ushort_t* _l = &lsh[(buf)*2][aoff + (mh)*4096]; \
    _Pragma("unroll") \
    for(int _m=0;_m<4;_m++){ \
      af[_m][0] = *(const s8v*)(_l + _m*1024 + k0s); \
      af[_m][1] = *(const s8v*)(_l + _m*1024 + k1s); \
    } \
  }while(0)

#define DSB(buf, nh) do{ \
    const ushort_t* _l = &lsh[(buf)*2+1][boff]; \
    _Pragma("unroll") \
    for(int _n=0;_n<2;_n++){ \
      bf[(nh)*2+_n][0] = *(const s8v*)(_l + ((nh)*2+_n)*1024 + k0s); \
      bf[(nh)*2+_n][1] = *(const s8v*)(_l + ((nh)*2+_n)*1024 + k1s); \
    } \
  }while(0)

#define MMP(mh, nh) do{ \
    __builtin_amdgcn_s_setprio(1); \
    _Pragma("unroll") \
    for(int _m=0;_m<4;_m++) \
      _Pragma("unroll") \
      for(int _n=0;_n<2;_n++){ \
        acc[(mh)*4+_m][(nh)*2+_n] = MFMA(af[_m][0], bf[(nh)*2+_n][0], acc[(mh)*4+_m][(nh)*2+_n]); \
        acc[(mh)*4+_m][(nh)*2+_n] = MFMA(af[_m][1], bf[(nh)*2+_n][1], acc[(mh)*4+_m][(nh)*2+_n]); \
      } \
    __builtin_amdgcn_s_setprio(0); \
  }while(0)

#define BARX  __builtin_amdgcn_s_barrier()
#define LGKM0 do{ asm volatile("s_waitcnt lgkmcnt(0)" ::: "memory"); __builtin_amdgcn_sched_barrier(0); }while(0)
#define VM2   do{ asm volatile("s_waitcnt vmcnt(2)"   ::: "memory"); __builtin_amdgcn_sched_barrier(0); }while(0)

  STG(0,0,0,0); STG(0,0,1,0); STG(0,1,0,0); STG(0,1,1,0);
  STG(1,0,0,1);
  VM2;
  BARX;

  for(int p=0; p<NP; p++){
    const int t1 = 2*p+1;
    const int t2 = (2*p+2 < KT)? 2*p+2 : KT-1;
    const int t3 = (2*p+3 < KT)? 2*p+3 : KT-1;
    DSA(0,0); DSB(0,0); STG(1,0,1,t1);
    asm volatile("s_waitcnt lgkmcnt(8)" ::: "memory");
    BARX; LGKM0; MMP(0,0); BARX;
    DSB(0,1); STG(1,1,0,t1); STG(1,1,1,t1);
    BARX; LGKM0; MMP(0,1); BARX;
    DSA(0,1); STG(0,0,0,t2);
    BARX; LGKM0; MMP(1,0); BARX;
    MMP(1,1); VM2; BARX;
    DSA(1,0); DSB(1,0); STG(0,0,1,t2);
    asm volatile("s_waitcnt lgkmcnt(8)" ::: "memory");
    BARX; LGKM0; MMP(0,0); BARX;
    DSB(1,1); STG(0,1,0,t2); STG(0,1,1,t2);
    BARX; LGKM0; MMP(0,1); BARX;
    DSA(1,1); STG(1,0,0,t3);
    BARX; LGKM0; MMP(1,0); BARX;
    MMP(1,1); VM2; BARX;
  }
  asm volatile("s_waitcnt vmcnt(0)" ::: "memory");

  #pragma unroll
  for(int m=0;m<8;m++){
    const int row = row0 + wm*128 + (m>>2)*64 + (m&3)*16 + quad*4;
    #pragma unroll
    for(int n=0;n<4;n++){
      const int col = col0 + wn*64 + n*16 + lid;
      float bv = 0.f;
      if(MODE>=1) bv = bias[col];
      #pragma unroll
      for(int rr=0;rr<4;rr++){
        float v = acc[m][n][rr] + bv;
        if(MODE==2) v = v>0.f ? v : (__expf(v) - 1.0f);   // fast ELU (bf16-accurate)
        Cc[(size_t)(row+rr)*ldc + col] = f2bf(v);
      }
    }
  }
#undef STG
#undef DSA
#undef DSB
#undef MMP
#undef BARX
#undef LGKM0
#undef VM2
}

// ---------------- kv^T partials + ksum ----------------
__global__ __launch_bounds__(256) void k_kv(const ushort_t* __restrict__ qkv,
    const ushort_t* __restrict__ projS,
    float* __restrict__ kvp, float* __restrict__ ksum)
{
  __shared__ ushort_t lK[64*64];
  __shared__ ushort_t lvT[2][64*72];
  __shared__ ushort_t lkp[64*72];
  const int chunk=blockIdx.x, mt=blockIdx.y, bh=blockIdx.z;
  const int h=bh&15, b=bh>>4;
  const int tid=threadIdx.x, wave=tid>>6, lane=tid&63, quad=lane>>4, lid=lane&15;

  s8v pf[4][2];
  {
    const ushort_t* projM = projS + mt*64*64;
    #pragma unroll
    for(int n=0;n<4;n++)
      #pragma unroll
      for(int ks=0;ks<2;ks++)
        pf[n][ks] = *(const s8v*)(projM + (n*16+lid)*64 + ks*32 + quad*8);
  }
  f4v kvacc[4];
  #pragma unroll
  for(int j=0;j<4;j++){ f4v z={0.f,0.f,0.f,0.f}; kvacc[j]=z; }
  float ksacc[4] = {};

  const int sl = tid>>3;
  const int gcb = (tid&7) ^ (sl&7);
  const size_t lbase = (size_t)(b*4096 + chunk*1024);
  const ushort_t* gK0 = qkv + (lbase + sl     )*3072 + 1024 + h*64 + gcb*8;
  const ushort_t* gK1 = qkv + (lbase + sl + 32)*3072 + 1024 + h*64 + gcb*8;
  ushort_t* lK0 = &lK[(wave*8     )*64];
  ushort_t* lK1 = &lK[(wave*8 + 32)*64];
  const ushort_t* gV = qkv + (lbase + lane)*3072 + 2048 + h*64 + wave*16;

  for(int it=0; it<16; it++){
    const int p = it&1;
    GLDS16(gK0, lK0);
    GLDS16(gK1, lK1);
    {
      s8v v0 = *(const s8v*)gV;
      s8v v1 = *(const s8v*)(gV + 8);
      #pragma unroll
      for(int jj=0;jj<8;jj++){
        lvT[p][(wave*16+jj  )*72 + lane] = (ushort_t)v0[jj];
        lvT[p][(wave*16+8+jj)*72 + lane] = (ushort_t)v1[jj];
      }
    }
    gK0 += 64*3072; gK1 += 64*3072; gV += 64*3072;
    __syncthreads();
    float dv;
    {
      const int rl = wave*16 + (lane>>2);
      const int cb0 = 2*(lane&3);
      s8v u0 = *(const s8v*)&lK[rl*64 + ((cb0  )^(rl&7))*8];
      s8v u1 = *(const s8v*)&lK[rl*64 + ((cb0+1)^(rl&7))*8];
      float s = 0.f;
      #pragma unroll
      for(int jj=0;jj<8;jj++){
        float f0=bf2f(u0[jj]), f1=bf2f(u1[jj]);
        s += f0*f0 + f1*f1;
      }
      s += __shfl_xor(s,1,64); s += __shfl_xor(s,2,64);
      dv = s*(1.f/16.f);
    }
    f4v dd[4];
    #pragma unroll
    for(int n=0;n<4;n++){ f4v z={0.f,0.f,0.f,0.f}; dd[n]=z; }
    {
      const int ra = wave*16 + lid;
      #pragma unroll
      for(int ks=0;ks<2;ks++){
        s8v af = *(const s8v*)&lK[ra*64 + ((ks*4+quad)^(ra&7))*8];
        #pragma unroll
        for(int n=0;n<4;n++) dd[n] = MFMA(af, pf[n][ks], dd[n]);
      }
    }
    const int lrb = wave*16 + quad*4;
    #pragma unroll
    for(int n=0;n<4;n++){
      s4v pk;
      #pragma unroll
      for(int r=0;r<4;r++){
        float dg = __shfl(dv, (quad*4+r)*4, 64);
        float ekp = __expf(dd[n][r] - dg) + 1e-6f;
        ksacc[n] += ekp;
        pk[r] = (short)f2bf(ekp);
      }
      *(s4v*)&lkp[(n*16+lid)*72 + lrb] = pk;
    }
    __syncthreads();
    #pragma unroll
    for(int ks=0;ks<2;ks++){
      s8v af = *(const s8v*)&lkp[(wave*16+lid)*72 + ks*32 + quad*8];
      #pragma unroll
      for(int j=0;j<4;j++){
        s8v bfr = *(const s8v*)&lvT[p][(j*16+lid)*72 + ks*32 + quad*8];
        kvacc[j] = MFMA(af, bfr, kvacc[j]);
      }
    }
  }
  #pragma unroll
  for(int n=0;n<4;n++){
    float s = ksacc[n];
    s += __shfl_xor(s,16,64); s += __shfl_xor(s,32,64);
    if(quad==0) atomicAdd(&ksum[((size_t)b*16+h)*256 + mt*64 + n*16 + lid], s);
  }
  float* kvo = kvp + ((size_t)chunk*64 + bh)*16384;
  #pragma unroll
  for(int j=0;j<4;j++)
    #pragma unroll
    for(int r=0;r<4;r++)
      kvo[(mt*64 + wave*16 + quad*4 + r)*64 + j*16 + lid] = kvacc[j][r];
}

// ---------------- reduce 4 kv partials + transpose to bf16 [dh][m] ----------------
__global__ __launch_bounds__(256) void k_f2bt(const float* __restrict__ kvp,
    ushort_t* __restrict__ kvb)
{
  __shared__ ushort_t tb[64*68];
  const int mt=blockIdx.x, bh=blockIdx.y;
  const int tid=threadIdx.x;
  {
    const int ml=tid>>2, dg=(tid&3)*16;
    float s[16];
    #pragma unroll
    for(int e=0;e<16;e++) s[e]=0.f;
    #pragma unroll
    for(int c=0;c<4;c++){
      const float* pb = kvp + ((size_t)(c*64+bh)*256 + mt*64+ml)*64 + dg;
      #pragma unroll
      for(int e4=0;e4<4;e4++){
        f4v v = *(const f4v*)(pb + e4*4);
        #pragma unroll
        for(int j=0;j<4;j++) s[e4*4+j] += v[j];
      }
    }
    #pragma unroll
    for(int e=0;e<16;e++) tb[ml*68 + dg + e] = f2bf(s[e]);
  }
  __syncthreads();
  {
    const int dh=tid>>2, mg=(tid&3)*16;
    ushort_t* ob = kvb + (size_t)bh*16384 + (size_t)dh*256 + mt*64 + mg;
    #pragma unroll
    for(int e4=0;e4<4;e4++){
      s4v o;
      #pragma unroll
      for(int j=0;j<4;j++) o[j] = (short)tb[(mg+e4*4+j)*68 + dh];
      *(s4v*)(ob + e4*4) = o;
    }
  }
}

// ---------------- fused attention (per b,h,128 rows) ----------------
__global__ __launch_bounds__(256,3) void k_attn(const ushort_t* __restrict__ qkv,
    const ushort_t* __restrict__ projS, const ushort_t* __restrict__ kvT,
    const float* __restrict__ ksum, ushort_t* __restrict__ attnW)
{
  __shared__ ushort_t lkv[64*256];   // [dh][m], col-blocks XOR-swizzled by dh&7
  __shared__ ushort_t lqp[64*136];   // [l][m-chunk], stride 136
  const int lt=blockIdx.x, h=blockIdx.y, b=blockIdx.z;
  const int tid=threadIdx.x, wave=tid>>6, lane=tid&63, quad=lane>>4, lid=lane&15;
  const ushort_t* kvbG = kvT + ((size_t)b*16+h)*(64*256);
  const float* ksb = ksum + ((size_t)b*16+h)*256;
  float kse[16];
  #pragma unroll
  for(int n=0;n<16;n++) kse[n] = ksb[n*16+lid];
  const int sdh = tid>>5;            // staging: row-in-group 0..7
  const int scb = tid&31;            // staging: 8-elem col-block

  #pragma unroll
  for(int t=0;t<2;t++){
    const int l0 = lt*128 + t*64;
    const ushort_t* qbase = qkv + (size_t)(b*4096+l0+wave*16+lid)*3072 + h*64;
    const s8v af0 = *(const s8v*)(qbase + quad*8);
    const s8v af1 = *(const s8v*)(qbase + 32 + quad*8);
    f4v num[4];
    #pragma unroll
    for(int j=0;j<4;j++){ f4v z={0.f,0.f,0.f,0.f}; num[j]=z; }
    float dnm[4] = {0.f,0.f,0.f,0.f};

    #pragma unroll
    for(int mc=0; mc<2; mc++){
      f4v dd[8];
      #pragma unroll
      for(int n=0;n<8;n++){ f4v z={0.f,0.f,0.f,0.f}; dd[n]=z; }
      #pragma unroll
      for(int n=0;n<8;n++){
        const ushort_t* pb = projS + ((mc*8+n)*16+lid)*64 + quad*8;
        s8v b0 = *(const s8v*)(pb);
        s8v b1 = *(const s8v*)(pb + 32);
        dd[n] = MFMA(af0, b0, dd[n]);
        dd[n] = MFMA(af1, b1, dd[n]);
      }
      if(t==0 && mc==0){
        __builtin_amdgcn_sched_barrier(0);
        #pragma unroll
        for(int q=0;q<8;q++){
          const int dh = q*8 + sdh;
          GLDS16(kvbG + dh*256 + ((scb ^ (dh&7))*8),
                 &lkv[(size_t)(q*8 + wave*2)*256]);
        }
        __builtin_amdgcn_sched_barrier(0);
      }
      #pragma unroll
      for(int r=0;r<4;r++){
        const int lrow = wave*16 + quad*4 + r;
        #pragma unroll
        for(int n=0;n<8;n++){
          float e = __expf(dd[n][r]) + 1e-6f;
          dnm[r] += e * kse[mc*8+n];
          lqp[lrow*136 + n*16 + lid] = f2bf(e);
        }
      }
      if(t==0 && mc==0){
        asm volatile("s_waitcnt vmcnt(0)" ::: "memory");
        __syncthreads();
      } else {
        asm volatile("s_waitcnt lgkmcnt(0)" ::: "memory");
        __builtin_amdgcn_sched_barrier(0);
      }
      #pragma unroll
      for(int ks=0;ks<4;ks++){
        s8v a = *(const s8v*)&lqp[(wave*16+lid)*136 + ks*32 + quad*8];
        #pragma unroll
        for(int j=0;j<4;j++){
          const int cbr = mc*16 + ks*4 + quad;
          s8v bfr = *(const s8v*)&lkv[(size_t)(j*16+lid)*256 + ((cbr ^ (lid&7))*8)];
          num[j] = MFMA(a, bfr, num[j]);
        }
      }
      asm volatile("s_waitcnt lgkmcnt(0)" ::: "memory");
      __builtin_amdgcn_sched_barrier(0);
    }
    #pragma unroll
    for(int r=0;r<4;r++){
      float s = dnm[r];
      s += __shfl_xor(s,1,64); s += __shfl_xor(s,2,64);
      s += __shfl_xor(s,4,64); s += __shfl_xor(s,8,64);
      dnm[r] = s;
    }
    #pragma unroll
    for(int j=0;j<4;j++)
      #pragma unroll
      for(int r=0;r<4;r++){
        const int row = b*4096 + l0 + wave*16 + quad*4 + r;
        attnW[(size_t)row*3072 + h*64 + j*16 + lid] = f2bf(num[j][r] / dnm[r]);
      }
  }
}

// ---------------- LayerNorm: wave-per-row, no barriers, no LDS (BISECT: only new change) ----------------
template<int FINAL>
__global__ __launch_bounds__(256) void k_ln(const float* __restrict__ xres,
    const ushort_t* __restrict__ aa, int lda_a,
    const ushort_t* __restrict__ bbf, int lda_b,
    const float* __restrict__ g, const float* __restrict__ be,
    ushort_t* __restrict__ obf, int ldo, float* __restrict__ of)
{
  const int w = threadIdx.x>>6, lane = threadIdx.x&63;
  const int row = blockIdx.x*4 + w;
  float v[16];
  #pragma unroll
  for(int k=0;k<4;k++){
    const int c = lane*4 + k*256;
    if(FINAL==0){
      f4v xv = *(const f4v*)(xres + (size_t)row*1024 + c);
      s4v av = *(const s4v*)(aa + (size_t)row*lda_a + c);
      #pragma unroll
      for(int j=0;j<4;j++) v[k*4+j] = xv[j] + bf2f(av[j]);
    } else {
      s4v av = *(const s4v*)(aa + (size_t)row*lda_a + c);
      s4v bv = *(const s4v*)(bbf + (size_t)row*lda_b + c);
      #pragma unroll
      for(int j=0;j<4;j++) v[k*4+j] = bf2f(av[j]) + bf2f(bv[j]);
    }
  }
  float s = 0.f;
  #pragma unroll
  for(int e=0;e<16;e++) s += v[e];
  #pragma unroll
  for(int o=1;o<64;o<<=1) s += __shfl_xor(s, o, 64);
  const float mu = s * (1.f/1024.f);
  float q = 0.f;
  #pragma unroll
  for(int e=0;e<16;e++){ float d=v[e]-mu; q += d*d; }
  #pragma unroll
  for(int o=1;o<64;o<<=1) q += __shfl_xor(q, o, 64);
  const float rs = rsqrtf(q*(1.f/1024.f) + 1e-6f);
  #pragma unroll
  for(int k=0;k<4;k++){
    const int c = lane*4 + k*256;
    f4v gv = *(const f4v*)(g + c);
    f4v bev = *(const f4v*)(be + c);
    if(FINAL==0){
      s4v o;
      #pragma unroll
      for(int j=0;j<4;j++) o[j] = (short)f2bf((v[k*4+j]-mu)*rs*gv[j] + bev[j]);
      *(s4v*)(obf + (size_t)row*ldo + c) = o;
    } else {
      f4v o;
      #pragma unroll
      for(int j=0;j<4;j++) o[j] = (v[k*4+j]-mu)*rs*gv[j] + bev[j];
      *(f4v*)(of + (size_t)row*1024 + c) = o;
    }
  }
}

// ---------------- launch ----------------
extern "C" void kernel_launch(void* const* d_in, const int* in_sizes, int n_in,
                              void* d_out, int out_size, void* d_ws, size_t ws_size,
                              hipStream_t stream) {
  (void)in_sizes; (void)n_in; (void)out_size;
  const float* x    = (const float*)d_in[0];
  const float* wq   = (const float*)d_in[1];
  const float* wk   = (const float*)d_in[2];
  const float* wv   = (const float*)d_in[3];
  const float* wo   = (const float*)d_in[4];
  const float* proj = (const float*)d_in[5];
  const float* ln1g = (const float*)d_in[6];
  const float* ln1b = (const float*)d_in[7];
  const float* ln2g = (const float*)d_in[8];
  const float* ln2b = (const float*)d_in[9];
  const float* w1   = (const float*)d_in[10];
  const float* b1   = (const float*)d_in[11];
  const float* w2   = (const float*)d_in[12];
  const float* b2   = (const float*)d_in[13];

  char* wsb = (char*)d_ws;
  size_t off = 0;
  auto alloc = [&](size_t bytes)->char*{
    char* p = wsb + off; off = (off + bytes + 255) & ~(size_t)255; return p;
  };
  ushort_t* wqkvT = (ushort_t*)alloc(3072ull*1024*2);
  ushort_t* woT   = (ushort_t*)alloc(1024ull*1024*2);
  ushort_t* w1T   = (ushort_t*)alloc(4096ull*1024*2);
  ushort_t* w2T   = (ushort_t*)alloc(1024ull*4096*2);
  ushort_t* projS = (ushort_t*)alloc(256*64*2);
  ushort_t* qkv   = (ushort_t*)alloc(16384ull*3072*2);
  size_t zoff = off;
  float*    ksumb = (float*)alloc(4ull*16*256*4);
  size_t zlen = off - zoff;
  ushort_t* kvb   = (ushort_t*)alloc(4ull*16*64*256*2);

  // FFN hidden buffer: prefer workspace (full 16384 rows, FFN2 gets a
  // full-GPU 256-block grid); fall back to d_out + 2-chunk if ws too small.
  const size_t hbBytes = 16384ull*4096*2;   // 128 MB
  ushort_t* hbWS = nullptr;
  if(off + hbBytes <= ws_size) hbWS = (ushort_t*)alloc(hbBytes);

  ushort_t* out1 = qkv;
  ushort_t* ao   = qkv + 1024;
  ushort_t* attn = qkv + 2048;
  ushort_t* ffn  = qkv + 2048;
  ushort_t* xb   = (ushort_t*)d_out;
  float*    kvp  = (float*)d_out;

  k_cvt_t<<<dim3(16,16),256,0,stream>>>(wq, wqkvT,                1024, 1024);
  k_cvt_t<<<dim3(16,16),256,0,stream>>>(wk, wqkvT + 1024ull*1024, 1024, 1024);
  k_cvt_t<<<dim3(16,16),256,0,stream>>>(wv, wqkvT + 2048ull*1024, 1024, 1024);
  k_cvt_t<<<dim3(16,16),256,0,stream>>>(wo, woT, 1024, 1024);
  k_cvt_t<<<dim3(64,16),256,0,stream>>>(w1, w1T, 4096, 1024);
  k_cvt_t<<<dim3(16,64),256,0,stream>>>(w2, w2T, 1024, 4096);
  k_proj<<<64,256,0,stream>>>(proj, projS);
  k_f2b4<<<16384,256,0,stream>>>(x, xb, 16384*1024/4);
  {
    int nz = (int)(zlen/4);
    k_zero<<<(nz+255)/256,256,0,stream>>>((float*)(wsb+zoff), nz);
  }

  // QKV projection
  gemm8<0><<<dim3(64,12),512,0,stream>>>(xb, 1024, wqkvT, 1024, qkv, 3072, nullptr, 16384, 3072, 1024, 4);
  k_kv<<<dim3(4,4,64),256,0,stream>>>(qkv, projS, kvp, ksumb);
  k_f2bt<<<dim3(4,64),256,0,stream>>>(kvp, kvb);
  k_attn<<<dim3(32,16,4),256,0,stream>>>(qkv, projS, kvb, ksumb, attn);
  // output projection + LN1
  gemm8<0><<<dim3(64,4),512,0,stream>>>(attn, 3072, woT, 1024, ao, 3072, nullptr, 16384, 1024, 1024, 4);
  k_ln<0><<<4096,256,0,stream>>>(x, ao, 3072, nullptr, 0, ln1g, ln1b, out1, 3072, nullptr);
  // FFN
  if(hbWS){
    gemm8<2><<<dim3(64,16),512,0,stream>>>(out1, 3072, w1T, 1024, hbWS, 4096, b1, 16384, 4096, 1024, 8);
    gemm8<1><<<dim3(64,4),512,0,stream>>>(hbWS, 4096, w2T, 4096, ffn, 3072, b2, 16384, 1024, 4096, 4);
  } else {
    ushort_t* hb = (ushort_t*)d_out;   // kvp dead by now
    for(int c=0;c<2;c++){
      const size_t ro = (size_t)c*8192*3072;
      gemm8<2><<<dim3(32,16),512,0,stream>>>(out1 + ro, 3072, w1T, 1024, hb, 4096, b1, 8192, 4096, 1024, 8);
      gemm8<1><<<dim3(32,4),512,0,stream>>>(hb, 4096, w2T, 4096, ffn + ro, 3072, b2, 8192, 1024, 4096, 4);
    }
  }
  // LN2 -> fp32 out (overwrites all of d_out)
  k_ln<1><<<4096,256,0,stream>>>(nullptr, out1, 3072, ffn, 3072, ln2g, ln2b, nullptr, 0, (float*)d_out);
}